// Round 1
// baseline (4212.176 us; speedup 1.0000x reference)
//
#include <hip/hip_runtime.h>

#define USER_NUM 100000
#define ITEM_NUM 50000
#define DD 64
#define NEDGE 3200000
#define NB 16384
#define NSLOT 256   // partial-accumulator slots per reduction target

__device__ __forceinline__ float waveReduceSum(float x) {
#pragma unroll
    for (int off = 32; off > 0; off >>= 1)
        x += __shfl_down(x, off, 64);
    return x;  // valid on lane 0
}

// One wave per edge; lane = feature. Scatters BOTH directions:
//   outU[u] += scale*v*srcI[i];  outI[i] += scale*v*srcU[u]
__global__ void __launch_bounds__(256) spmm_both(
    const int* __restrict__ eu, const int* __restrict__ ei,
    const float* __restrict__ ev,
    const float* __restrict__ srcU,   // [USER_NUM, DD]
    const float* __restrict__ srcI,   // [ITEM_NUM, DD]
    float* __restrict__ outU,         // [USER_NUM, DD]
    float* __restrict__ outI,         // [ITEM_NUM, DD]
    float scale) {
    const int lane = threadIdx.x & 63;
    const int wave = blockIdx.x * (blockDim.x >> 6) + (threadIdx.x >> 6);
    const int nwave = gridDim.x * (blockDim.x >> 6);
    for (int e = wave; e < NEDGE; e += nwave) {
        const int u = eu[e];
        const int i = ei[e];
        const float v = ev[e] * scale;
        const float a = srcI[i * DD + lane];
        const float b = srcU[u * DD + lane];
        unsafeAtomicAdd(&outU[u * DD + lane], v * a);
        unsafeAtomicAdd(&outI[i * DD + lane], v * b);
    }
}

// A = emb + 0.5*A + (1/3)*B   (elementwise, float4)
__global__ void __launch_bounds__(256) combine(
    const float4* __restrict__ emb, const float4* __restrict__ Bv,
    float4* __restrict__ Av, int n4) {
    int i = blockIdx.x * blockDim.x + threadIdx.x;
    if (i < n4) {
        float4 e = emb[i], b = Bv[i], a = Av[i];
        const float c3 = 1.0f / 3.0f;
        a.x = e.x + 0.5f * a.x + c3 * b.x;
        a.y = e.y + 0.5f * a.y + c3 * b.y;
        a.z = e.z + 0.5f * a.z + c3 * b.z;
        a.w = e.w + 0.5f * a.w + c3 * b.w;
        Av[i] = a;
    }
}

// One wave per BPR sample. accs layout: [bpr | reg | selfU | selfI] x NSLOT
__global__ void __launch_bounds__(256) bpr_loss(
    const int* __restrict__ user, const int* __restrict__ itemI,
    const int* __restrict__ itemJ,
    const float* __restrict__ gcnU, const float* __restrict__ gcnI,
    float* __restrict__ accs) {
    const int lane = threadIdx.x & 63;
    const int wave = blockIdx.x * (blockDim.x >> 6) + (threadIdx.x >> 6);
    if (wave >= NB) return;
    const int uu = user[wave], vi = itemI[wave], vj = itemJ[wave];
    const float u  = gcnU[uu * DD + lane];
    const float xi = gcnI[vi * DD + lane];
    const float xj = gcnI[vj * DD + lane];
    const float pi = waveReduceSum(u * xi);
    const float pj = waveReduceSum(u * xj);
    const float rg = waveReduceSum(u * u + xi * xi + xj * xj);
    if (lane == 0) {
        const float x = pi - pj;
        // -log_sigmoid(x) = softplus(-x), numerically stable
        const float bpr = fmaxf(-x, 0.0f) + log1pf(expf(-fabsf(x)));
        const int slot = wave & (NSLOT - 1);
        unsafeAtomicAdd(&accs[0 * NSLOT + slot], bpr);
        unsafeAtomicAdd(&accs[1 * NSLOT + slot], rg);
    }
}

// One wave per row over users then items: sqrt(sum((old-gcn)^2)) * n[row]
__global__ void __launch_bounds__(256) self_loss(
    const float* __restrict__ oldU, const float* __restrict__ oldI,
    const float* __restrict__ gcnU, const float* __restrict__ gcnI,
    const float* __restrict__ nU, const float* __restrict__ nI,
    float* __restrict__ accs) {
    const int lane = threadIdx.x & 63;
    const int wave = blockIdx.x * (blockDim.x >> 6) + (threadIdx.x >> 6);
    if (wave < USER_NUM) {
        const float d = oldU[wave * DD + lane] - gcnU[wave * DD + lane];
        const float s = waveReduceSum(d * d);
        if (lane == 0)
            unsafeAtomicAdd(&accs[2 * NSLOT + (wave & (NSLOT - 1))], sqrtf(s) * nU[wave]);
    } else if (wave < USER_NUM + ITEM_NUM) {
        const int r = wave - USER_NUM;
        const float d = oldI[r * DD + lane] - gcnI[r * DD + lane];
        const float s = waveReduceSum(d * d);
        if (lane == 0)
            unsafeAtomicAdd(&accs[3 * NSLOT + (r & (NSLOT - 1))], sqrtf(s) * nI[r]);
    }
}

__global__ void __launch_bounds__(64) finalize(const float* __restrict__ accs,
                                              float* __restrict__ out) {
    const int lane = threadIdx.x;
    float s[4];
#pragma unroll
    for (int k = 0; k < 4; k++) {
        float v = 0.0f;
        for (int j = lane; j < NSLOT; j += 64) v += accs[k * NSLOT + j];
        s[k] = waveReduceSum(v);
    }
    if (lane == 0) {
        const float loss_bpr = s[0] / NB + 1e-4f * (s[1] / NB);
        const float loss_self = s[2] / USER_NUM + s[3] / ITEM_NUM;
        out[0] = loss_bpr;
        out[1] = 100.0f * loss_self;
        out[2] = 1.0f;
        out[3] = 1.0f;
    }
}

extern "C" void kernel_launch(void* const* d_in, const int* in_sizes, int n_in,
                              void* d_out, int out_size, void* d_ws, size_t ws_size,
                              hipStream_t stream) {
    const int*   user     = (const int*)d_in[0];
    const int*   item_i   = (const int*)d_in[1];
    const int*   item_j   = (const int*)d_in[2];
    const int*   edge_u   = (const int*)d_in[3];
    const int*   edge_i   = (const int*)d_in[4];
    const float* edge_val = (const float*)d_in[5];
    const float* user_emb = (const float*)d_in[6];
    const float* item_emb = (const float*)d_in[7];
    const float* old_U    = (const float*)d_in[8];
    const float* old_I    = (const float*)d_in[9];
    const float* n_U      = (const float*)d_in[10];
    const float* n_I      = (const float*)d_in[11];
    float* out = (float*)d_out;

    float* Au = (float*)d_ws;                    // g1u -> gcn_u  [USER_NUM*DD]
    float* Ai = Au + (size_t)USER_NUM * DD;      // g1i -> gcn_i  [ITEM_NUM*DD]
    float* Bu = Ai + (size_t)ITEM_NUM * DD;      // g2u           [USER_NUM*DD]
    float* Bi = Bu + (size_t)USER_NUM * DD;      // g2i           [ITEM_NUM*DD]
    float* accs = Bi + (size_t)ITEM_NUM * DD;    // 4*NSLOT partial sums

    const size_t zero_bytes =
        ((size_t)2 * (USER_NUM + ITEM_NUM) * DD + 4 * NSLOT) * sizeof(float);
    hipMemsetAsync(d_ws, 0, zero_bytes, stream);

    const dim3 blk(256);
    const int spmm_grid = 8192;  // 32768 waves, ~98 edges each

    // hop 1: A = g1
    spmm_both<<<spmm_grid, blk, 0, stream>>>(edge_u, edge_i, edge_val,
                                             user_emb, item_emb, Au, Ai, 1.0f);
    // hop 2: B = g2 (from A=g1)
    spmm_both<<<spmm_grid, blk, 0, stream>>>(edge_u, edge_i, edge_val,
                                             Au, Ai, Bu, Bi, 1.0f);
    // A = emb + 0.5*g1 + (1/3)*g2
    combine<<<(USER_NUM * DD / 4 + 255) / 256, blk, 0, stream>>>(
        (const float4*)user_emb, (const float4*)Bu, (float4*)Au, USER_NUM * DD / 4);
    combine<<<(ITEM_NUM * DD / 4 + 255) / 256, blk, 0, stream>>>(
        (const float4*)item_emb, (const float4*)Bi, (float4*)Ai, ITEM_NUM * DD / 4);
    // hop 3: A += 0.25*g3 (scatter from B=g2 directly, scaled) -> A = gcn
    spmm_both<<<spmm_grid, blk, 0, stream>>>(edge_u, edge_i, edge_val,
                                             Bu, Bi, Au, Ai, 0.25f);
    // losses
    bpr_loss<<<(NB + 3) / 4, blk, 0, stream>>>(user, item_i, item_j, Au, Ai, accs);
    self_loss<<<(USER_NUM + ITEM_NUM + 3) / 4, blk, 0, stream>>>(
        old_U, old_I, Au, Ai, n_U, n_I, accs);
    finalize<<<1, 64, 0, stream>>>(accs, out);
}

// Round 2
// 2131.419 us; speedup vs baseline: 1.9762x; 1.9762x over previous
//
#include <hip/hip_runtime.h>

#define USER_NUM 100000
#define ITEM_NUM 50000
#define DD 64
#define NEDGE 3200000
#define NB 16384
#define NSLOT 256

__device__ __forceinline__ float waveReduceSum(float x) {
#pragma unroll
    for (int off = 32; off > 0; off >>= 1)
        x += __shfl_down(x, off, 64);
    return x;
}

// ---------- counting-sort build (CSR by destination, both directions) ----------

__global__ void __launch_bounds__(256) hist_kernel(
    const int* __restrict__ eu, const int* __restrict__ ei,
    int* __restrict__ cntU, int* __restrict__ cntI) {
    int idx = blockIdx.x * blockDim.x + threadIdx.x;
    int stride = gridDim.x * blockDim.x;
    for (int e = idx; e < NEDGE; e += stride) {
        atomicAdd(&cntU[eu[e]], 1);
        atomicAdd(&cntI[ei[e]], 1);
    }
}

// two blocks: block 0 scans users, block 1 scans items. Writes rowPtr (excl
// prefix, N+1 entries) and cursor (= rowPtr[i]) for the scatter pass.
__global__ void __launch_bounds__(1024) scan2_kernel(
    const int* __restrict__ cntU, int* __restrict__ rpU, int* __restrict__ curU,
    const int* __restrict__ cntI, int* __restrict__ rpI, int* __restrict__ curI) {
    const int* cnt; int* rp; int* cur; int n;
    if (blockIdx.x == 0) { cnt = cntU; rp = rpU; cur = curU; n = USER_NUM; }
    else                 { cnt = cntI; rp = rpI; cur = curI; n = ITEM_NUM; }
    __shared__ int part[1024];
    const int t = threadIdx.x;
    const int chunk = (n + 1023) >> 10;
    const int lo = t * chunk;
    const int hi = min(lo + chunk, n);
    int s = 0;
    for (int i = lo; i < hi; i++) s += cnt[i];
    part[t] = s;
    __syncthreads();
    for (int off = 1; off < 1024; off <<= 1) {
        int v = (t >= off) ? part[t - off] : 0;
        __syncthreads();
        part[t] += v;
        __syncthreads();
    }
    int run = (t == 0) ? 0 : part[t - 1];
    for (int i = lo; i < hi; i++) {
        rp[i] = run; cur[i] = run; run += cnt[i];
    }
    if (t == 1023) rp[n] = part[1023];
}

__global__ void __launch_bounds__(256) scatter_kernel(
    const int* __restrict__ eu, const int* __restrict__ ei,
    const float* __restrict__ ev,
    int* __restrict__ curU, int* __restrict__ curI,
    int* __restrict__ idxU, float* __restrict__ valU,
    int* __restrict__ idxI, float* __restrict__ valI) {
    int idx = blockIdx.x * blockDim.x + threadIdx.x;
    int stride = gridDim.x * blockDim.x;
    for (int e = idx; e < NEDGE; e += stride) {
        const int u = eu[e], i = ei[e];
        const float v = ev[e];
        const int p = atomicAdd(&curU[u], 1);
        idxU[p] = i; valU[p] = v;
        const int q = atomicAdd(&curI[i], 1);
        idxI[q] = u; valI[q] = v;
    }
}

// ---------- gather-based SpMM hop (both directions in one dispatch) ----------
// wave per destination row, lane = feature. fused==1: hop-3 epilogue
// out = emb + 0.5*g1 + (1/3)*g2 + 0.25*acc   (out may alias g1 — same-row RMW)
__global__ void __launch_bounds__(256) gather_hop(
    const int* __restrict__ rpU, const int* __restrict__ idxU,
    const float* __restrict__ valU, const float* __restrict__ srcForU,
    float* __restrict__ outU,
    const int* __restrict__ rpI, const int* __restrict__ idxI,
    const float* __restrict__ valI, const float* __restrict__ srcForI,
    float* __restrict__ outI,
    const float* __restrict__ embU, const float* __restrict__ g1u,
    const float* __restrict__ g2u,
    const float* __restrict__ embI, const float* __restrict__ g1i,
    const float* __restrict__ g2i,
    int fused) {
    const int lane = threadIdx.x & 63;
    const int wave = blockIdx.x * (blockDim.x >> 6) + (threadIdx.x >> 6);
    const int* rp; const int* sidx; const float* sval;
    const float* src; float* out;
    const float *emb, *g1, *g2;
    int row;
    if (wave < USER_NUM) {
        row = wave;
        rp = rpU; sidx = idxU; sval = valU; src = srcForU; out = outU;
        emb = embU; g1 = g1u; g2 = g2u;
    } else if (wave < USER_NUM + ITEM_NUM) {
        row = wave - USER_NUM;
        rp = rpI; sidx = idxI; sval = valI; src = srcForI; out = outI;
        emb = embI; g1 = g1i; g2 = g2i;
    } else {
        return;
    }
    const int s = rp[row], e2 = rp[row + 1];
    float acc0 = 0.0f, acc1 = 0.0f;
    int t = s;
    for (; t + 1 < e2; t += 2) {
        const int s0 = sidx[t], s1 = sidx[t + 1];
        const float v0 = sval[t], v1 = sval[t + 1];
        acc0 += v0 * src[s0 * DD + lane];
        acc1 += v1 * src[s1 * DD + lane];
    }
    if (t < e2) acc0 += sval[t] * src[sidx[t] * DD + lane];
    const float acc = acc0 + acc1;
    const int o = row * DD + lane;
    if (fused)
        out[o] = emb[o] + 0.5f * g1[o] + (1.0f / 3.0f) * g2[o] + 0.25f * acc;
    else
        out[o] = acc;
}

// ---------- losses ----------

__global__ void __launch_bounds__(256) bpr_loss(
    const int* __restrict__ user, const int* __restrict__ itemI,
    const int* __restrict__ itemJ,
    const float* __restrict__ gcnU, const float* __restrict__ gcnI,
    float* __restrict__ accs) {
    const int lane = threadIdx.x & 63;
    const int wave = blockIdx.x * (blockDim.x >> 6) + (threadIdx.x >> 6);
    if (wave >= NB) return;
    const int uu = user[wave], vi = itemI[wave], vj = itemJ[wave];
    const float u  = gcnU[uu * DD + lane];
    const float xi = gcnI[vi * DD + lane];
    const float xj = gcnI[vj * DD + lane];
    const float pi = waveReduceSum(u * xi);
    const float pj = waveReduceSum(u * xj);
    const float rg = waveReduceSum(u * u + xi * xi + xj * xj);
    if (lane == 0) {
        const float x = pi - pj;
        const float bpr = fmaxf(-x, 0.0f) + log1pf(expf(-fabsf(x)));
        const int slot = wave & (NSLOT - 1);
        unsafeAtomicAdd(&accs[0 * NSLOT + slot], bpr);
        unsafeAtomicAdd(&accs[1 * NSLOT + slot], rg);
    }
}

__global__ void __launch_bounds__(256) self_loss(
    const float* __restrict__ oldU, const float* __restrict__ oldI,
    const float* __restrict__ gcnU, const float* __restrict__ gcnI,
    const float* __restrict__ nU, const float* __restrict__ nI,
    float* __restrict__ accs) {
    const int lane = threadIdx.x & 63;
    const int wave = blockIdx.x * (blockDim.x >> 6) + (threadIdx.x >> 6);
    if (wave < USER_NUM) {
        const float d = oldU[wave * DD + lane] - gcnU[wave * DD + lane];
        const float s = waveReduceSum(d * d);
        if (lane == 0)
            unsafeAtomicAdd(&accs[2 * NSLOT + (wave & (NSLOT - 1))], sqrtf(s) * nU[wave]);
    } else if (wave < USER_NUM + ITEM_NUM) {
        const int r = wave - USER_NUM;
        const float d = oldI[r * DD + lane] - gcnI[r * DD + lane];
        const float s = waveReduceSum(d * d);
        if (lane == 0)
            unsafeAtomicAdd(&accs[3 * NSLOT + (r & (NSLOT - 1))], sqrtf(s) * nI[r]);
    }
}

__global__ void __launch_bounds__(64) finalize(const float* __restrict__ accs,
                                               float* __restrict__ out) {
    const int lane = threadIdx.x;
    float s[4];
#pragma unroll
    for (int k = 0; k < 4; k++) {
        float v = 0.0f;
        for (int j = lane; j < NSLOT; j += 64) v += accs[k * NSLOT + j];
        s[k] = waveReduceSum(v);
    }
    if (lane == 0) {
        const float loss_bpr = s[0] / NB + 1e-4f * (s[1] / NB);
        const float loss_self = s[2] / USER_NUM + s[3] / ITEM_NUM;
        out[0] = loss_bpr;
        out[1] = 100.0f * loss_self;
        out[2] = 1.0f;
        out[3] = 1.0f;
    }
}

extern "C" void kernel_launch(void* const* d_in, const int* in_sizes, int n_in,
                              void* d_out, int out_size, void* d_ws, size_t ws_size,
                              hipStream_t stream) {
    const int*   user     = (const int*)d_in[0];
    const int*   item_i   = (const int*)d_in[1];
    const int*   item_j   = (const int*)d_in[2];
    const int*   edge_u   = (const int*)d_in[3];
    const int*   edge_i   = (const int*)d_in[4];
    const float* edge_val = (const float*)d_in[5];
    const float* user_emb = (const float*)d_in[6];
    const float* item_emb = (const float*)d_in[7];
    const float* old_U    = (const float*)d_in[8];
    const float* old_I    = (const float*)d_in[9];
    const float* n_U      = (const float*)d_in[10];
    const float* n_I      = (const float*)d_in[11];
    float* out = (float*)d_out;

    // workspace layout (elements of 4 B). Zeroed region first.
    int*   cntU = (int*)d_ws;                     // USER_NUM
    int*   cntI = cntU + USER_NUM;                // ITEM_NUM
    float* accs = (float*)(cntI + ITEM_NUM);      // 4*NSLOT
    int*   rpU  = (int*)(accs + 4 * NSLOT);       // USER_NUM+1
    int*   rpI  = rpU + USER_NUM + 1;             // ITEM_NUM+1
    int*   curU = rpI + ITEM_NUM + 1;             // USER_NUM
    int*   curI = curU + USER_NUM;                // ITEM_NUM
    int*   idxU = curI + ITEM_NUM;                // NEDGE
    float* valU = (float*)(idxU + NEDGE);         // NEDGE
    int*   idxI = (int*)(valU + NEDGE);           // NEDGE
    float* valI = (float*)(idxI + NEDGE);         // NEDGE
    float* g1u  = valI + NEDGE;                   // USER_NUM*DD
    float* g1i  = g1u + (size_t)USER_NUM * DD;    // ITEM_NUM*DD
    float* g2u  = g1i + (size_t)ITEM_NUM * DD;    // USER_NUM*DD
    float* g2i  = g2u + (size_t)USER_NUM * DD;    // ITEM_NUM*DD

    const size_t zero_bytes = ((size_t)USER_NUM + ITEM_NUM + 4 * NSLOT) * 4;
    hipMemsetAsync(d_ws, 0, zero_bytes, stream);

    const dim3 blk(256);

    // build CSR (both directions) via counting sort
    hist_kernel<<<2048, blk, 0, stream>>>(edge_u, edge_i, cntU, cntI);
    scan2_kernel<<<2, 1024, 0, stream>>>(cntU, rpU, curU, cntI, rpI, curI);
    scatter_kernel<<<2048, blk, 0, stream>>>(edge_u, edge_i, edge_val,
                                             curU, curI, idxU, valU, idxI, valI);

    const int rows = USER_NUM + ITEM_NUM;
    const int hop_grid = (rows + 3) / 4;  // 4 waves per 256-thread block

    // hop 1: g1 = A @ emb
    gather_hop<<<hop_grid, blk, 0, stream>>>(
        rpU, idxU, valU, item_emb, g1u,
        rpI, idxI, valI, user_emb, g1i,
        nullptr, nullptr, nullptr, nullptr, nullptr, nullptr, 0);
    // hop 2: g2 = A @ g1
    gather_hop<<<hop_grid, blk, 0, stream>>>(
        rpU, idxU, valU, g1i, g2u,
        rpI, idxI, valI, g1u, g2i,
        nullptr, nullptr, nullptr, nullptr, nullptr, nullptr, 0);
    // hop 3 fused: gcn = emb + 0.5*g1 + (1/3)*g2 + 0.25*(A @ g2); write into g1
    gather_hop<<<hop_grid, blk, 0, stream>>>(
        rpU, idxU, valU, g2i, g1u,
        rpI, idxI, valI, g2u, g1i,
        user_emb, g1u, g2u, item_emb, g1i, g2i, 1);

    // losses (gcn lives in g1u/g1i)
    bpr_loss<<<(NB + 3) / 4, blk, 0, stream>>>(user, item_i, item_j, g1u, g1i, accs);
    self_loss<<<(USER_NUM + ITEM_NUM + 3) / 4, blk, 0, stream>>>(
        old_U, old_I, g1u, g1i, n_U, n_I, accs);
    finalize<<<1, 64, 0, stream>>>(accs, out);
}

// Round 3
// 1959.094 us; speedup vs baseline: 2.1501x; 1.0880x over previous
//
#include <hip/hip_runtime.h>

#define USER_NUM 100000
#define ITEM_NUM 50000
#define DD 64
#define NEDGE 3200000
#define NB 16384
#define NSLOT 256

__device__ __forceinline__ float waveReduceSum(float x) {
#pragma unroll
    for (int off = 32; off > 0; off >>= 1)
        x += __shfl_down(x, off, 64);
    return x;
}

// ---------- counting-sort build (CSR by destination, both directions) ----------

__global__ void __launch_bounds__(256) hist_kernel(
    const int* __restrict__ eu, const int* __restrict__ ei,
    int* __restrict__ cntU, int* __restrict__ cntI) {
    int idx = blockIdx.x * blockDim.x + threadIdx.x;
    int stride = gridDim.x * blockDim.x;
    for (int e = idx; e < NEDGE; e += stride) {
        atomicAdd(&cntU[eu[e]], 1);
        atomicAdd(&cntI[ei[e]], 1);
    }
}

__global__ void __launch_bounds__(1024) scan2_kernel(
    const int* __restrict__ cntU, int* __restrict__ rpU, int* __restrict__ curU,
    const int* __restrict__ cntI, int* __restrict__ rpI, int* __restrict__ curI) {
    const int* cnt; int* rp; int* cur; int n;
    if (blockIdx.x == 0) { cnt = cntU; rp = rpU; cur = curU; n = USER_NUM; }
    else                 { cnt = cntI; rp = rpI; cur = curI; n = ITEM_NUM; }
    __shared__ int part[1024];
    const int t = threadIdx.x;
    const int chunk = (n + 1023) >> 10;
    const int lo = t * chunk;
    const int hi = min(lo + chunk, n);
    int s = 0;
    for (int i = lo; i < hi; i++) s += cnt[i];
    part[t] = s;
    __syncthreads();
    for (int off = 1; off < 1024; off <<= 1) {
        int v = (t >= off) ? part[t - off] : 0;
        __syncthreads();
        part[t] += v;
        __syncthreads();
    }
    int run = (t == 0) ? 0 : part[t - 1];
    for (int i = lo; i < hi; i++) {
        rp[i] = run; cur[i] = run; run += cnt[i];
    }
    if (t == 1023) rp[n] = part[1023];
}

__global__ void __launch_bounds__(256) scatter_kernel(
    const int* __restrict__ eu, const int* __restrict__ ei,
    const float* __restrict__ ev,
    int* __restrict__ curU, int* __restrict__ curI,
    int2* __restrict__ ivU, int2* __restrict__ ivI) {
    int idx = blockIdx.x * blockDim.x + threadIdx.x;
    int stride = gridDim.x * blockDim.x;
    for (int e = idx; e < NEDGE; e += stride) {
        const int u = eu[e], i = ei[e];
        const int vb = __float_as_int(ev[e]);
        const int p = atomicAdd(&curU[u], 1);
        ivU[p] = make_int2(i, vb);
        const int q = atomicAdd(&curI[i], 1);
        ivI[q] = make_int2(u, vb);
    }
}

// ---------- gather-based SpMM hop (both directions in one dispatch) ----------
// lane = sub*16 + r: sub picks one of 4 edges/iter, r picks float4 feature chunk.
// fused==1 adds the hop-3 epilogue: out = emb + 0.5*g1 + (1/3)*g2 + 0.25*acc
__global__ void __launch_bounds__(256) gather_hop(
    const int* __restrict__ rpU, const int2* __restrict__ ivU,
    const float* __restrict__ srcForU, float* __restrict__ outU,
    const int* __restrict__ rpI, const int2* __restrict__ ivI,
    const float* __restrict__ srcForI, float* __restrict__ outI,
    const float* __restrict__ embU, const float* __restrict__ g1u,
    const float* __restrict__ g2u,
    const float* __restrict__ embI, const float* __restrict__ g1i,
    const float* __restrict__ g2i,
    int fused) {
    const int lane = threadIdx.x & 63;
    const int sub = lane >> 4;
    const int r = lane & 15;
    const int wave = blockIdx.x * (blockDim.x >> 6) + (threadIdx.x >> 6);
    const int* rp; const int2* iv; const float* src; float* out;
    const float *emb, *g1, *g2;
    int row;
    if (wave < USER_NUM) {
        row = wave;
        rp = rpU; iv = ivU; src = srcForU; out = outU;
        emb = embU; g1 = g1u; g2 = g2u;
    } else if (wave < USER_NUM + ITEM_NUM) {
        row = wave - USER_NUM;
        rp = rpI; iv = ivI; src = srcForI; out = outI;
        emb = embI; g1 = g1i; g2 = g2i;
    } else {
        return;
    }
    const int s = rp[row], e2 = rp[row + 1];
    float4 a0 = make_float4(0.f, 0.f, 0.f, 0.f);
    float4 a1 = make_float4(0.f, 0.f, 0.f, 0.f);
    int t = s + sub;
    for (; t + 4 < e2; t += 8) {
        const int2 x0 = iv[t];
        const int2 x1 = iv[t + 4];
        const float v0 = __int_as_float(x0.y);
        const float v1 = __int_as_float(x1.y);
        const float4 s0 = *(const float4*)&src[x0.x * DD + r * 4];
        const float4 s1 = *(const float4*)&src[x1.x * DD + r * 4];
        a0.x += v0 * s0.x; a0.y += v0 * s0.y; a0.z += v0 * s0.z; a0.w += v0 * s0.w;
        a1.x += v1 * s1.x; a1.y += v1 * s1.y; a1.z += v1 * s1.z; a1.w += v1 * s1.w;
    }
    if (t < e2) {
        const int2 x0 = iv[t];
        const float v0 = __int_as_float(x0.y);
        const float4 s0 = *(const float4*)&src[x0.x * DD + r * 4];
        a0.x += v0 * s0.x; a0.y += v0 * s0.y; a0.z += v0 * s0.z; a0.w += v0 * s0.w;
    }
    float4 acc;
    acc.x = a0.x + a1.x; acc.y = a0.y + a1.y;
    acc.z = a0.z + a1.z; acc.w = a0.w + a1.w;
#pragma unroll
    for (int off = 16; off <= 32; off <<= 1) {
        acc.x += __shfl_xor(acc.x, off, 64);
        acc.y += __shfl_xor(acc.y, off, 64);
        acc.z += __shfl_xor(acc.z, off, 64);
        acc.w += __shfl_xor(acc.w, off, 64);
    }
    if (sub == 0) {
        const int o4 = row * 16 + r;  // float4 index
        if (fused) {
            const float4 e = ((const float4*)emb)[o4];
            const float4 p1 = ((const float4*)g1)[o4];
            const float4 p2 = ((const float4*)g2)[o4];
            const float c3 = 1.0f / 3.0f;
            acc.x = e.x + 0.5f * p1.x + c3 * p2.x + 0.25f * acc.x;
            acc.y = e.y + 0.5f * p1.y + c3 * p2.y + 0.25f * acc.y;
            acc.z = e.z + 0.5f * p1.z + c3 * p2.z + 0.25f * acc.z;
            acc.w = e.w + 0.5f * p1.w + c3 * p2.w + 0.25f * acc.w;
        }
        ((float4*)out)[o4] = acc;
    }
}

// ---------- losses ----------

__global__ void __launch_bounds__(256) bpr_loss(
    const int* __restrict__ user, const int* __restrict__ itemI,
    const int* __restrict__ itemJ,
    const float* __restrict__ gcnU, const float* __restrict__ gcnI,
    float* __restrict__ accs) {
    const int lane = threadIdx.x & 63;
    const int wave = blockIdx.x * (blockDim.x >> 6) + (threadIdx.x >> 6);
    if (wave >= NB) return;
    const int uu = user[wave], vi = itemI[wave], vj = itemJ[wave];
    const float u  = gcnU[uu * DD + lane];
    const float xi = gcnI[vi * DD + lane];
    const float xj = gcnI[vj * DD + lane];
    const float pi = waveReduceSum(u * xi);
    const float pj = waveReduceSum(u * xj);
    const float rg = waveReduceSum(u * u + xi * xi + xj * xj);
    if (lane == 0) {
        const float x = pi - pj;
        const float bpr = fmaxf(-x, 0.0f) + log1pf(expf(-fabsf(x)));
        const int slot = wave & (NSLOT - 1);
        unsafeAtomicAdd(&accs[0 * NSLOT + slot], bpr);
        unsafeAtomicAdd(&accs[1 * NSLOT + slot], rg);
    }
}

__global__ void __launch_bounds__(256) self_loss(
    const float* __restrict__ oldU, const float* __restrict__ oldI,
    const float* __restrict__ gcnU, const float* __restrict__ gcnI,
    const float* __restrict__ nU, const float* __restrict__ nI,
    float* __restrict__ accs) {
    const int lane = threadIdx.x & 63;
    const int wave = blockIdx.x * (blockDim.x >> 6) + (threadIdx.x >> 6);
    if (wave < USER_NUM) {
        const float d = oldU[wave * DD + lane] - gcnU[wave * DD + lane];
        const float s = waveReduceSum(d * d);
        if (lane == 0)
            unsafeAtomicAdd(&accs[2 * NSLOT + (wave & (NSLOT - 1))], sqrtf(s) * nU[wave]);
    } else if (wave < USER_NUM + ITEM_NUM) {
        const int r = wave - USER_NUM;
        const float d = oldI[r * DD + lane] - gcnI[r * DD + lane];
        const float s = waveReduceSum(d * d);
        if (lane == 0)
            unsafeAtomicAdd(&accs[3 * NSLOT + (r & (NSLOT - 1))], sqrtf(s) * nI[r]);
    }
}

__global__ void __launch_bounds__(64) finalize(const float* __restrict__ accs,
                                               float* __restrict__ out) {
    const int lane = threadIdx.x;
    float s[4];
#pragma unroll
    for (int k = 0; k < 4; k++) {
        float v = 0.0f;
        for (int j = lane; j < NSLOT; j += 64) v += accs[k * NSLOT + j];
        s[k] = waveReduceSum(v);
    }
    if (lane == 0) {
        const float loss_bpr = s[0] / NB + 1e-4f * (s[1] / NB);
        const float loss_self = s[2] / USER_NUM + s[3] / ITEM_NUM;
        out[0] = loss_bpr;
        out[1] = 100.0f * loss_self;
        out[2] = 1.0f;
        out[3] = 1.0f;
    }
}

extern "C" void kernel_launch(void* const* d_in, const int* in_sizes, int n_in,
                              void* d_out, int out_size, void* d_ws, size_t ws_size,
                              hipStream_t stream) {
    const int*   user     = (const int*)d_in[0];
    const int*   item_i   = (const int*)d_in[1];
    const int*   item_j   = (const int*)d_in[2];
    const int*   edge_u   = (const int*)d_in[3];
    const int*   edge_i   = (const int*)d_in[4];
    const float* edge_val = (const float*)d_in[5];
    const float* user_emb = (const float*)d_in[6];
    const float* item_emb = (const float*)d_in[7];
    const float* old_U    = (const float*)d_in[8];
    const float* old_I    = (const float*)d_in[9];
    const float* n_U      = (const float*)d_in[10];
    const float* n_I      = (const float*)d_in[11];
    float* out = (float*)d_out;

    // byte-offset carve-outs, each 256-B aligned
    char* base = (char*)d_ws;
    size_t off = 0;
    auto carve = [&](size_t bytes) {
        char* p = base + off;
        off += (bytes + 255) & ~(size_t)255;
        return p;
    };
    int*   cntU = (int*)carve(USER_NUM * 4);
    int*   cntI = (int*)carve(ITEM_NUM * 4);
    float* accs = (float*)carve(4 * NSLOT * 4);
    size_t zero_bytes = off;  // everything above must start at 0
    int*   rpU  = (int*)carve((USER_NUM + 1) * 4);
    int*   rpI  = (int*)carve((ITEM_NUM + 1) * 4);
    int*   curU = (int*)carve(USER_NUM * 4);
    int*   curI = (int*)carve(ITEM_NUM * 4);
    int2*  ivU  = (int2*)carve((size_t)NEDGE * 8);
    int2*  ivI  = (int2*)carve((size_t)NEDGE * 8);
    float* g1u  = (float*)carve((size_t)USER_NUM * DD * 4);
    float* g1i  = (float*)carve((size_t)ITEM_NUM * DD * 4);
    float* g2u  = (float*)carve((size_t)USER_NUM * DD * 4);
    float* g2i  = (float*)carve((size_t)ITEM_NUM * DD * 4);

    hipMemsetAsync(d_ws, 0, zero_bytes, stream);

    const dim3 blk(256);

    hist_kernel<<<2048, blk, 0, stream>>>(edge_u, edge_i, cntU, cntI);
    scan2_kernel<<<2, 1024, 0, stream>>>(cntU, rpU, curU, cntI, rpI, curI);
    scatter_kernel<<<2048, blk, 0, stream>>>(edge_u, edge_i, edge_val,
                                             curU, curI, ivU, ivI);

    const int rows = USER_NUM + ITEM_NUM;
    const int hop_grid = (rows + 3) / 4;  // 4 waves per 256-thread block

    gather_hop<<<hop_grid, blk, 0, stream>>>(
        rpU, ivU, item_emb, g1u,
        rpI, ivI, user_emb, g1i,
        nullptr, nullptr, nullptr, nullptr, nullptr, nullptr, 0);
    gather_hop<<<hop_grid, blk, 0, stream>>>(
        rpU, ivU, g1i, g2u,
        rpI, ivI, g1u, g2i,
        nullptr, nullptr, nullptr, nullptr, nullptr, nullptr, 0);
    gather_hop<<<hop_grid, blk, 0, stream>>>(
        rpU, ivU, g2i, g1u,
        rpI, ivI, g2u, g1i,
        user_emb, g1u, g2u, item_emb, g1i, g2i, 1);

    bpr_loss<<<(NB + 3) / 4, blk, 0, stream>>>(user, item_i, item_j, g1u, g1i, accs);
    self_loss<<<(USER_NUM + ITEM_NUM + 3) / 4, blk, 0, stream>>>(
        old_U, old_I, g1u, g1i, n_U, n_I, accs);
    finalize<<<1, 64, 0, stream>>>(accs, out);
}

// Round 4
// 1793.860 us; speedup vs baseline: 2.3481x; 1.0921x over previous
//
#include <hip/hip_runtime.h>

#define USER_NUM 100000
#define ITEM_NUM 50000
#define DD 64
#define NEDGE 3200000
#define NB 16384
#define NSLOT 256

__device__ __forceinline__ float waveReduceSum(float x) {
#pragma unroll
    for (int off = 32; off > 0; off >>= 1)
        x += __shfl_down(x, off, 64);
    return x;
}

// ---- bf16 pack/unpack (pair in one uint: elem0 = low 16, elem1 = high 16) ----
__device__ __forceinline__ unsigned pack_bf2(float a, float b) {
    unsigned ua = __float_as_uint(a), ub = __float_as_uint(b);
    ua = (ua + 0x7fffu + ((ua >> 16) & 1u)) >> 16;
    ub = (ub + 0x7fffu + ((ub >> 16) & 1u)) & 0xffff0000u;
    return ua | ub;
}
__device__ __forceinline__ float bf_lo(unsigned u) { return __uint_as_float(u << 16); }
__device__ __forceinline__ float bf_hi(unsigned u) { return __uint_as_float(u & 0xffff0000u); }

// fp32 table -> bf16 table (uint2 = 4 features)
__global__ void __launch_bounds__(256) cvt_kernel(
    const float4* __restrict__ src, uint2* __restrict__ dst, int n4) {
    int t = blockIdx.x * blockDim.x + threadIdx.x;
    if (t < n4) {
        float4 f = src[t];
        dst[t] = make_uint2(pack_bf2(f.x, f.y), pack_bf2(f.z, f.w));
    }
}

// ---------- counting-sort build (CSR by destination, both directions) ----------
// 4 edges per thread via int4; 3125 blocks x 256 threads covers NEDGE exactly.

__global__ void __launch_bounds__(256) hist_kernel(
    const int4* __restrict__ eu4, const int4* __restrict__ ei4,
    int* __restrict__ cntU, int* __restrict__ cntI) {
    int t = blockIdx.x * blockDim.x + threadIdx.x;
    int4 u = eu4[t];
    int4 i = ei4[t];
    atomicAdd(&cntU[u.x], 1); atomicAdd(&cntU[u.y], 1);
    atomicAdd(&cntU[u.z], 1); atomicAdd(&cntU[u.w], 1);
    atomicAdd(&cntI[i.x], 1); atomicAdd(&cntI[i.y], 1);
    atomicAdd(&cntI[i.z], 1); atomicAdd(&cntI[i.w], 1);
}

__global__ void __launch_bounds__(1024) scan2_kernel(
    const int* __restrict__ cntU, int* __restrict__ rpU, int* __restrict__ curU,
    const int* __restrict__ cntI, int* __restrict__ rpI, int* __restrict__ curI) {
    const int* cnt; int* rp; int* cur; int n;
    if (blockIdx.x == 0) { cnt = cntU; rp = rpU; cur = curU; n = USER_NUM; }
    else                 { cnt = cntI; rp = rpI; cur = curI; n = ITEM_NUM; }
    __shared__ int part[1024];
    const int t = threadIdx.x;
    const int chunk = (n + 1023) >> 10;
    const int lo = t * chunk;
    const int hi = min(lo + chunk, n);
    int s = 0;
    for (int i = lo; i < hi; i++) s += cnt[i];
    part[t] = s;
    __syncthreads();
    for (int off = 1; off < 1024; off <<= 1) {
        int v = (t >= off) ? part[t - off] : 0;
        __syncthreads();
        part[t] += v;
        __syncthreads();
    }
    int run = (t == 0) ? 0 : part[t - 1];
    for (int i = lo; i < hi; i++) {
        rp[i] = run; cur[i] = run; run += cnt[i];
    }
    if (t == 1023) rp[n] = part[1023];
}

// 4 edges/thread: all 8 cursor atomics issued back-to-back (independent), then
// all 8 payload stores — ~1 atomic round-trip of latency per thread, not 8.
__global__ void __launch_bounds__(256) scatter_kernel(
    const int4* __restrict__ eu4, const int4* __restrict__ ei4,
    const float4* __restrict__ ev4,
    int* __restrict__ curU, int* __restrict__ curI,
    int2* __restrict__ ivU, int2* __restrict__ ivI) {
    int t = blockIdx.x * blockDim.x + threadIdx.x;
    int4 u = eu4[t];
    int4 i = ei4[t];
    float4 v = ev4[t];
    int p0 = atomicAdd(&curU[u.x], 1);
    int p1 = atomicAdd(&curU[u.y], 1);
    int p2 = atomicAdd(&curU[u.z], 1);
    int p3 = atomicAdd(&curU[u.w], 1);
    int q0 = atomicAdd(&curI[i.x], 1);
    int q1 = atomicAdd(&curI[i.y], 1);
    int q2 = atomicAdd(&curI[i.z], 1);
    int q3 = atomicAdd(&curI[i.w], 1);
    ivU[p0] = make_int2(i.x, __float_as_int(v.x));
    ivU[p1] = make_int2(i.y, __float_as_int(v.y));
    ivU[p2] = make_int2(i.z, __float_as_int(v.z));
    ivU[p3] = make_int2(i.w, __float_as_int(v.w));
    ivI[q0] = make_int2(u.x, __float_as_int(v.x));
    ivI[q1] = make_int2(u.y, __float_as_int(v.y));
    ivI[q2] = make_int2(u.z, __float_as_int(v.z));
    ivI[q3] = make_int2(u.w, __float_as_int(v.w));
}

// ---------- gather hop core: bf16 source rows, fp32 accumulate ----------
// lane = sub*16 + r; sub picks 1 of 4 edges/iter; r picks 4-feature chunk.
__device__ __forceinline__ float4 row_accum(
    const int* __restrict__ rp, const int2* __restrict__ iv,
    const uint2* __restrict__ src, int row, int sub, int r) {
    const int s = rp[row], e2 = rp[row + 1];
    float4 a0 = make_float4(0.f, 0.f, 0.f, 0.f);
    float4 a1 = make_float4(0.f, 0.f, 0.f, 0.f);
    int t = s + sub;
    for (; t + 4 < e2; t += 8) {
        const int2 x0 = iv[t];
        const int2 x1 = iv[t + 4];
        const float v0 = __int_as_float(x0.y);
        const float v1 = __int_as_float(x1.y);
        const uint2 b0 = src[x0.x * 16 + r];
        const uint2 b1 = src[x1.x * 16 + r];
        a0.x += v0 * bf_lo(b0.x); a0.y += v0 * bf_hi(b0.x);
        a0.z += v0 * bf_lo(b0.y); a0.w += v0 * bf_hi(b0.y);
        a1.x += v1 * bf_lo(b1.x); a1.y += v1 * bf_hi(b1.x);
        a1.z += v1 * bf_lo(b1.y); a1.w += v1 * bf_hi(b1.y);
    }
    if (t < e2) {
        const int2 x0 = iv[t];
        const float v0 = __int_as_float(x0.y);
        const uint2 b0 = src[x0.x * 16 + r];
        a0.x += v0 * bf_lo(b0.x); a0.y += v0 * bf_hi(b0.x);
        a0.z += v0 * bf_lo(b0.y); a0.w += v0 * bf_hi(b0.y);
    }
    float4 acc;
    acc.x = a0.x + a1.x; acc.y = a0.y + a1.y;
    acc.z = a0.z + a1.z; acc.w = a0.w + a1.w;
#pragma unroll
    for (int off = 16; off <= 32; off <<= 1) {
        acc.x += __shfl_xor(acc.x, off, 64);
        acc.y += __shfl_xor(acc.y, off, 64);
        acc.z += __shfl_xor(acc.z, off, 64);
        acc.w += __shfl_xor(acc.w, off, 64);
    }
    return acc;  // valid on sub==0
}

// hops 1 & 2: out is bf16
__global__ void __launch_bounds__(256) gather_hop_bf(
    const int* __restrict__ rpU, const int2* __restrict__ ivU,
    const uint2* __restrict__ srcForU, uint2* __restrict__ outU,
    const int* __restrict__ rpI, const int2* __restrict__ ivI,
    const uint2* __restrict__ srcForI, uint2* __restrict__ outI) {
    const int lane = threadIdx.x & 63;
    const int sub = lane >> 4;
    const int r = lane & 15;
    const int wave = blockIdx.x * (blockDim.x >> 6) + (threadIdx.x >> 6);
    const int* rp; const int2* iv; const uint2* src; uint2* out; int row;
    if (wave < USER_NUM) {
        row = wave; rp = rpU; iv = ivU; src = srcForU; out = outU;
    } else if (wave < USER_NUM + ITEM_NUM) {
        row = wave - USER_NUM; rp = rpI; iv = ivI; src = srcForI; out = outI;
    } else return;
    float4 acc = row_accum(rp, iv, src, row, sub, r);
    if (sub == 0)
        out[row * 16 + r] = make_uint2(pack_bf2(acc.x, acc.y), pack_bf2(acc.z, acc.w));
}

// hop 3 fused epilogue: gcn = emb + 0.5*g1 + (1/3)*g2 + 0.25*acc, fp32 out
__global__ void __launch_bounds__(256) gather_hop3(
    const int* __restrict__ rpU, const int2* __restrict__ ivU,
    const uint2* __restrict__ srcForU,
    const int* __restrict__ rpI, const int2* __restrict__ ivI,
    const uint2* __restrict__ srcForI,
    const float4* __restrict__ embU, const uint2* __restrict__ g1u,
    const uint2* __restrict__ g2u, float4* __restrict__ gcnU,
    const float4* __restrict__ embI, const uint2* __restrict__ g1i,
    const uint2* __restrict__ g2i, float4* __restrict__ gcnI) {
    const int lane = threadIdx.x & 63;
    const int sub = lane >> 4;
    const int r = lane & 15;
    const int wave = blockIdx.x * (blockDim.x >> 6) + (threadIdx.x >> 6);
    const int* rp; const int2* iv; const uint2* src;
    const float4* emb; const uint2* g1; const uint2* g2; float4* gcn; int row;
    if (wave < USER_NUM) {
        row = wave; rp = rpU; iv = ivU; src = srcForU;
        emb = embU; g1 = g1u; g2 = g2u; gcn = gcnU;
    } else if (wave < USER_NUM + ITEM_NUM) {
        row = wave - USER_NUM; rp = rpI; iv = ivI; src = srcForI;
        emb = embI; g1 = g1i; g2 = g2i; gcn = gcnI;
    } else return;
    float4 acc = row_accum(rp, iv, src, row, sub, r);
    if (sub == 0) {
        const int o = row * 16 + r;
        const float4 e = emb[o];
        const uint2 p1 = g1[o];
        const uint2 p2 = g2[o];
        const float c3 = 1.0f / 3.0f;
        float4 g;
        g.x = e.x + 0.5f * bf_lo(p1.x) + c3 * bf_lo(p2.x) + 0.25f * acc.x;
        g.y = e.y + 0.5f * bf_hi(p1.x) + c3 * bf_hi(p2.x) + 0.25f * acc.y;
        g.z = e.z + 0.5f * bf_lo(p1.y) + c3 * bf_lo(p2.y) + 0.25f * acc.z;
        g.w = e.w + 0.5f * bf_hi(p1.y) + c3 * bf_hi(p2.y) + 0.25f * acc.w;
        gcn[o] = g;
    }
}

// ---------- losses ----------

__global__ void __launch_bounds__(256) bpr_loss(
    const int* __restrict__ user, const int* __restrict__ itemI,
    const int* __restrict__ itemJ,
    const float* __restrict__ gcnU, const float* __restrict__ gcnI,
    float* __restrict__ accs) {
    const int lane = threadIdx.x & 63;
    const int wave = blockIdx.x * (blockDim.x >> 6) + (threadIdx.x >> 6);
    if (wave >= NB) return;
    const int uu = user[wave], vi = itemI[wave], vj = itemJ[wave];
    const float u  = gcnU[uu * DD + lane];
    const float xi = gcnI[vi * DD + lane];
    const float xj = gcnI[vj * DD + lane];
    const float pi = waveReduceSum(u * xi);
    const float pj = waveReduceSum(u * xj);
    const float rg = waveReduceSum(u * u + xi * xi + xj * xj);
    if (lane == 0) {
        const float x = pi - pj;
        const float bpr = fmaxf(-x, 0.0f) + log1pf(expf(-fabsf(x)));
        const int slot = wave & (NSLOT - 1);
        unsafeAtomicAdd(&accs[0 * NSLOT + slot], bpr);
        unsafeAtomicAdd(&accs[1 * NSLOT + slot], rg);
    }
}

__global__ void __launch_bounds__(256) self_loss(
    const float* __restrict__ oldU, const float* __restrict__ oldI,
    const float* __restrict__ gcnU, const float* __restrict__ gcnI,
    const float* __restrict__ nU, const float* __restrict__ nI,
    float* __restrict__ accs) {
    const int lane = threadIdx.x & 63;
    const int wave = blockIdx.x * (blockDim.x >> 6) + (threadIdx.x >> 6);
    if (wave < USER_NUM) {
        const float d = oldU[wave * DD + lane] - gcnU[wave * DD + lane];
        const float s = waveReduceSum(d * d);
        if (lane == 0)
            unsafeAtomicAdd(&accs[2 * NSLOT + (wave & (NSLOT - 1))], sqrtf(s) * nU[wave]);
    } else if (wave < USER_NUM + ITEM_NUM) {
        const int r = wave - USER_NUM;
        const float d = oldI[r * DD + lane] - gcnI[r * DD + lane];
        const float s = waveReduceSum(d * d);
        if (lane == 0)
            unsafeAtomicAdd(&accs[3 * NSLOT + (r & (NSLOT - 1))], sqrtf(s) * nI[r]);
    }
}

__global__ void __launch_bounds__(64) finalize(const float* __restrict__ accs,
                                               float* __restrict__ out) {
    const int lane = threadIdx.x;
    float s[4];
#pragma unroll
    for (int k = 0; k < 4; k++) {
        float v = 0.0f;
        for (int j = lane; j < NSLOT; j += 64) v += accs[k * NSLOT + j];
        s[k] = waveReduceSum(v);
    }
    if (lane == 0) {
        const float loss_bpr = s[0] / NB + 1e-4f * (s[1] / NB);
        const float loss_self = s[2] / USER_NUM + s[3] / ITEM_NUM;
        out[0] = loss_bpr;
        out[1] = 100.0f * loss_self;
        out[2] = 1.0f;
        out[3] = 1.0f;
    }
}

extern "C" void kernel_launch(void* const* d_in, const int* in_sizes, int n_in,
                              void* d_out, int out_size, void* d_ws, size_t ws_size,
                              hipStream_t stream) {
    const int*   user     = (const int*)d_in[0];
    const int*   item_i   = (const int*)d_in[1];
    const int*   item_j   = (const int*)d_in[2];
    const int*   edge_u   = (const int*)d_in[3];
    const int*   edge_i   = (const int*)d_in[4];
    const float* edge_val = (const float*)d_in[5];
    const float* user_emb = (const float*)d_in[6];
    const float* item_emb = (const float*)d_in[7];
    const float* old_U    = (const float*)d_in[8];
    const float* old_I    = (const float*)d_in[9];
    const float* n_U      = (const float*)d_in[10];
    const float* n_I      = (const float*)d_in[11];
    float* out = (float*)d_out;

    char* base = (char*)d_ws;
    size_t off = 0;
    auto carve = [&](size_t bytes) {
        char* p = base + off;
        off += (bytes + 255) & ~(size_t)255;
        return p;
    };
    int*   cntU = (int*)carve(USER_NUM * 4);
    int*   cntI = (int*)carve(ITEM_NUM * 4);
    float* accs = (float*)carve(4 * NSLOT * 4);
    size_t zero_bytes = off;  // everything above must start zeroed
    int*   rpU  = (int*)carve((USER_NUM + 1) * 4);
    int*   rpI  = (int*)carve((ITEM_NUM + 1) * 4);
    int*   curU = (int*)carve(USER_NUM * 4);
    int*   curI = (int*)carve(ITEM_NUM * 4);
    int2*  ivU  = (int2*)carve((size_t)NEDGE * 8);
    int2*  ivI  = (int2*)carve((size_t)NEDGE * 8);
    uint2* ebU  = (uint2*)carve((size_t)USER_NUM * DD * 2);   // bf16 emb
    uint2* ebI  = (uint2*)carve((size_t)ITEM_NUM * DD * 2);
    uint2* g1u  = (uint2*)carve((size_t)USER_NUM * DD * 2);   // bf16 hop outs
    uint2* g1i  = (uint2*)carve((size_t)ITEM_NUM * DD * 2);
    uint2* g2u  = (uint2*)carve((size_t)USER_NUM * DD * 2);
    uint2* g2i  = (uint2*)carve((size_t)ITEM_NUM * DD * 2);
    float* gcnU = (float*)carve((size_t)USER_NUM * DD * 4);   // fp32 final
    float* gcnI = (float*)carve((size_t)ITEM_NUM * DD * 4);

    hipMemsetAsync(d_ws, 0, zero_bytes, stream);

    const dim3 blk(256);
    const int edge_grid = NEDGE / (256 * 4);  // 3125, exact

    // CSR build + bf16 table conversion
    hist_kernel<<<edge_grid, blk, 0, stream>>>((const int4*)edge_u,
                                               (const int4*)edge_i, cntU, cntI);
    cvt_kernel<<<(USER_NUM * 16 + 255) / 256, blk, 0, stream>>>(
        (const float4*)user_emb, ebU, USER_NUM * 16);
    cvt_kernel<<<(ITEM_NUM * 16 + 255) / 256, blk, 0, stream>>>(
        (const float4*)item_emb, ebI, ITEM_NUM * 16);
    scan2_kernel<<<2, 1024, 0, stream>>>(cntU, rpU, curU, cntI, rpI, curI);
    scatter_kernel<<<edge_grid, blk, 0, stream>>>(
        (const int4*)edge_u, (const int4*)edge_i, (const float4*)edge_val,
        curU, curI, ivU, ivI);

    const int rows = USER_NUM + ITEM_NUM;
    const int hop_grid = (rows + 3) / 4;

    gather_hop_bf<<<hop_grid, blk, 0, stream>>>(rpU, ivU, ebI, g1u,
                                                rpI, ivI, ebU, g1i);
    gather_hop_bf<<<hop_grid, blk, 0, stream>>>(rpU, ivU, g1i, g2u,
                                                rpI, ivI, g1u, g2i);
    gather_hop3<<<hop_grid, blk, 0, stream>>>(
        rpU, ivU, g2i, rpI, ivI, g2u,
        (const float4*)user_emb, g1u, g2u, (float4*)gcnU,
        (const float4*)item_emb, g1i, g2i, (float4*)gcnI);

    bpr_loss<<<(NB + 3) / 4, blk, 0, stream>>>(user, item_i, item_j, gcnU, gcnI, accs);
    self_loss<<<(rows + 3) / 4, blk, 0, stream>>>(
        old_U, old_I, gcnU, gcnI, n_U, n_I, accs);
    finalize<<<1, 64, 0, stream>>>(accs, out);
}

// Round 5
// 920.769 us; speedup vs baseline: 4.5746x; 1.9482x over previous
//
#include <hip/hip_runtime.h>

#define USER_NUM 100000
#define ITEM_NUM 50000
#define DD 64
#define NEDGE 3200000
#define NB 16384
#define NSLOT 256

#define TILE 8192
#define NTILE ((NEDGE + TILE - 1) / TILE)        // 391
#define USH 9                                    // user coarse bucket = 512 dests
#define ISH 8                                    // item coarse bucket = 256 dests
#define UBK ((USER_NUM + (1 << USH) - 1) >> USH) // 196
#define IBK ((ITEM_NUM + (1 << ISH) - 1) >> ISH) // 196
#define NBK (UBK + IBK)                          // 392

__device__ __forceinline__ float waveReduceSum(float x) {
#pragma unroll
    for (int off = 32; off > 0; off >>= 1)
        x += __shfl_down(x, off, 64);
    return x;
}

// ---- bf16 helpers ----
__device__ __forceinline__ unsigned pack_bf2(float a, float b) {
    unsigned ua = __float_as_uint(a), ub = __float_as_uint(b);
    ua = (ua + 0x7fffu + ((ua >> 16) & 1u)) >> 16;
    ub = (ub + 0x7fffu + ((ub >> 16) & 1u)) & 0xffff0000u;
    return ua | ub;
}
__device__ __forceinline__ float bf_lo(unsigned u) { return __uint_as_float(u << 16); }
__device__ __forceinline__ float bf_hi(unsigned u) { return __uint_as_float(u & 0xffff0000u); }
__device__ __forceinline__ unsigned roundbf(unsigned y) {  // fp32 bits -> bf16 bits (RNE)
    return (y + 0x7fffu + ((y >> 16) & 1u)) >> 16;
}

// fp32 table -> bf16 table (uint2 = 4 features)
__global__ void __launch_bounds__(256) cvt_kernel(
    const float4* __restrict__ src, uint2* __restrict__ dst, int n4) {
    int t = blockIdx.x * blockDim.x + threadIdx.x;
    if (t < n4) {
        float4 f = src[t];
        dst[t] = make_uint2(pack_bf2(f.x, f.y), pack_bf2(f.z, f.w));
    }
}

// ---------- two-level binned counting sort ----------
// Level 1: coarse bucket counts (LDS-aggregated -> 392 global atomics/tile)
__global__ void __launch_bounds__(256) coarse_hist(
    const int* __restrict__ eu, const int* __restrict__ ei,
    int* __restrict__ coarseCnt) {
    __shared__ int lc[NBK];
    const int t = threadIdx.x;
    for (int j = t; j < NBK; j += 256) lc[j] = 0;
    __syncthreads();
    const int tb = blockIdx.x * TILE;
    for (int k = 0; k < TILE / 256; k++) {
        int e = tb + k * 256 + t;
        if (e < NEDGE) {
            atomicAdd(&lc[eu[e] >> USH], 1);
            atomicAdd(&lc[UBK + (ei[e] >> ISH)], 1);
        }
    }
    __syncthreads();
    for (int j = t; j < NBK; j += 256)
        if (lc[j]) atomicAdd(&coarseCnt[j], lc[j]);
}

// scan coarse counts (two independent segments: U buckets, I buckets)
__global__ void __launch_bounds__(512) coarse_scan(
    const int* __restrict__ cnt, int* __restrict__ base, int* __restrict__ cur) {
    __shared__ int a[512];
    const int t = threadIdx.x;
    // U segment
    int v = (t < UBK) ? cnt[t] : 0;
    a[t] = v;
    __syncthreads();
    for (int off = 1; off < 512; off <<= 1) {
        int x = (t >= off) ? a[t - off] : 0;
        __syncthreads();
        a[t] += x;
        __syncthreads();
    }
    if (t < UBK) { base[t] = a[t] - v; cur[t] = a[t] - v; }
    __syncthreads();
    // I segment
    v = (t < IBK) ? cnt[UBK + t] : 0;
    a[t] = v;
    __syncthreads();
    for (int off = 1; off < 512; off <<= 1) {
        int x = (t >= off) ? a[t - off] : 0;
        __syncthreads();
        a[t] += x;
        __syncthreads();
    }
    if (t < IBK) { base[UBK + t] = a[t] - v; cur[UBK + t] = a[t] - v; }
}

// Level 2a: bin edges into coarse-bucket-grouped staging (contiguous runs per
// tile-bucket -> L2 write-merge; one global atomic per (tile,bucket)).
// staging U entry: x = (u_low9 << 16) | item16, y = fp32 val bits
// staging I entry: x = (i_low8 << 17) | user17, y = fp32 val bits
__global__ void __launch_bounds__(256) binA(
    const int* __restrict__ eu, const int* __restrict__ ei,
    const float* __restrict__ ev,
    int* __restrict__ coarseCur, int2* __restrict__ stU, int2* __restrict__ stI) {
    __shared__ int lc[NBK];
    const int t = threadIdx.x;
    for (int j = t; j < NBK; j += 256) lc[j] = 0;
    __syncthreads();
    const int tb = blockIdx.x * TILE;
    for (int k = 0; k < TILE / 256; k++) {
        int e = tb + k * 256 + t;
        if (e < NEDGE) {
            atomicAdd(&lc[eu[e] >> USH], 1);
            atomicAdd(&lc[UBK + (ei[e] >> ISH)], 1);
        }
    }
    __syncthreads();
    for (int j = t; j < NBK; j += 256) {
        int c = lc[j];
        lc[j] = c ? atomicAdd(&coarseCur[j], c) : 0;
    }
    __syncthreads();
    for (int k = 0; k < TILE / 256; k++) {
        int e = tb + k * 256 + t;
        if (e < NEDGE) {
            int u = eu[e], i = ei[e], vb = __float_as_int(ev[e]);
            int pu = atomicAdd(&lc[u >> USH], 1);
            stU[pu] = make_int2(((u & ((1 << USH) - 1)) << 16) | i, vb);
            int pi = atomicAdd(&lc[UBK + (i >> ISH)], 1);
            stI[pi] = make_int2(((i & ((1 << ISH) - 1)) << 17) | u, vb);
        }
    }
}

// Level 2b: one block per coarse bucket: LDS fine histogram + scan writes rp,
// then scatter final 4-byte entries (random writes confined to ~65 KB window).
// final U entry: (bf16val << 16) | item16
// final I entry: (val15 << 17) | user17   (val15 = sign-less bf16)
__global__ void __launch_bounds__(256) binB(
    const int2* __restrict__ stU, const int2* __restrict__ stI,
    const int* __restrict__ base, const int* __restrict__ cnt,
    int* __restrict__ rpU, int* __restrict__ rpI,
    unsigned* __restrict__ ivU, unsigned* __restrict__ ivI) {
    __shared__ int h[512];
    const int t = threadIdx.x;
    const int b = blockIdx.x;
    if (b < UBK) {
        const int s = base[b], n = cnt[b];
        const int dbase = b << USH;
        h[t] = 0; h[t + 256] = 0;
        __syncthreads();
        for (int p = s + t; p < s + n; p += 256)
            atomicAdd(&h[(unsigned)stU[p].x >> 16], 1);
        __syncthreads();
        int o0 = h[t], o1 = h[t + 256];
        for (int off = 1; off < 512; off <<= 1) {
            int x0 = (t >= off) ? h[t - off] : 0;
            int x1 = (t + 256 >= off) ? h[t + 256 - off] : 0;
            __syncthreads();
            h[t] += x0; h[t + 256] += x1;
            __syncthreads();
        }
        int e0 = s + h[t] - o0, e1 = s + h[t + 256] - o1;
        __syncthreads();
        h[t] = e0; h[t + 256] = e1;   // cursors == rp for these dests
        if (dbase + t < USER_NUM) rpU[dbase + t] = e0;
        if (dbase + 256 + t < USER_NUM) rpU[dbase + 256 + t] = e1;
        if (t == 0 && dbase + 512 >= USER_NUM) rpU[USER_NUM] = s + n;
        __syncthreads();
        for (int p = s + t; p < s + n; p += 256) {
            int2 en = stU[p];
            unsigned x = (unsigned)en.x;
            int pos = atomicAdd(&h[x >> 16], 1);
            unsigned bf = roundbf((unsigned)en.y);
            ivU[pos] = (bf << 16) | (x & 0xFFFFu);
        }
    } else {
        const int ib = b - UBK;
        const int s = base[b], n = cnt[b];
        const int dbase = ib << ISH;
        h[t] = 0;
        __syncthreads();
        for (int p = s + t; p < s + n; p += 256)
            atomicAdd(&h[(unsigned)stI[p].x >> 17], 1);
        __syncthreads();
        int o0 = h[t];
        for (int off = 1; off < 256; off <<= 1) {
            int x0 = (t >= off) ? h[t - off] : 0;
            __syncthreads();
            h[t] += x0;
            __syncthreads();
        }
        int e0 = s + h[t] - o0;
        __syncthreads();
        h[t] = e0;
        if (dbase + t < ITEM_NUM) rpI[dbase + t] = e0;
        if (t == 0 && dbase + 256 >= ITEM_NUM) rpI[ITEM_NUM] = s + n;
        __syncthreads();
        for (int p = s + t; p < s + n; p += 256) {
            int2 en = stI[p];
            unsigned x = (unsigned)en.x;
            int pos = atomicAdd(&h[x >> 17], 1);
            unsigned v15 = roundbf((unsigned)en.y) & 0x7FFFu;
            ivI[pos] = (v15 << 17) | (x & 0x1FFFFu);
        }
    }
}

// ---------- gather hop core: 4B edge entries, bf16 rows, fp32 accumulate ----------
template<bool ISU>
__device__ __forceinline__ float4 row_accum(
    const int* __restrict__ rp, const unsigned* __restrict__ iv,
    const uint2* __restrict__ src, int row, int sub, int r) {
    const int s = rp[row], e2 = rp[row + 1];
    float4 a0 = make_float4(0.f, 0.f, 0.f, 0.f);
    float4 a1 = make_float4(0.f, 0.f, 0.f, 0.f);
    int t = s + sub;
    for (; t + 4 < e2; t += 8) {
        const unsigned q0 = iv[t];
        const unsigned q1 = iv[t + 4];
        const float v0 = ISU ? __uint_as_float(q0 & 0xFFFF0000u)
                             : __uint_as_float((q0 >> 17) << 16);
        const float v1 = ISU ? __uint_as_float(q1 & 0xFFFF0000u)
                             : __uint_as_float((q1 >> 17) << 16);
        const int x0 = ISU ? (int)(q0 & 0xFFFFu) : (int)(q0 & 0x1FFFFu);
        const int x1 = ISU ? (int)(q1 & 0xFFFFu) : (int)(q1 & 0x1FFFFu);
        const uint2 b0 = src[x0 * 16 + r];
        const uint2 b1 = src[x1 * 16 + r];
        a0.x += v0 * bf_lo(b0.x); a0.y += v0 * bf_hi(b0.x);
        a0.z += v0 * bf_lo(b0.y); a0.w += v0 * bf_hi(b0.y);
        a1.x += v1 * bf_lo(b1.x); a1.y += v1 * bf_hi(b1.x);
        a1.z += v1 * bf_lo(b1.y); a1.w += v1 * bf_hi(b1.y);
    }
    if (t < e2) {
        const unsigned q0 = iv[t];
        const float v0 = ISU ? __uint_as_float(q0 & 0xFFFF0000u)
                             : __uint_as_float((q0 >> 17) << 16);
        const int x0 = ISU ? (int)(q0 & 0xFFFFu) : (int)(q0 & 0x1FFFFu);
        const uint2 b0 = src[x0 * 16 + r];
        a0.x += v0 * bf_lo(b0.x); a0.y += v0 * bf_hi(b0.x);
        a0.z += v0 * bf_lo(b0.y); a0.w += v0 * bf_hi(b0.y);
    }
    float4 acc;
    acc.x = a0.x + a1.x; acc.y = a0.y + a1.y;
    acc.z = a0.z + a1.z; acc.w = a0.w + a1.w;
#pragma unroll
    for (int off = 16; off <= 32; off <<= 1) {
        acc.x += __shfl_xor(acc.x, off, 64);
        acc.y += __shfl_xor(acc.y, off, 64);
        acc.z += __shfl_xor(acc.z, off, 64);
        acc.w += __shfl_xor(acc.w, off, 64);
    }
    return acc;  // valid on sub==0
}

// hops 1 & 2: out is bf16
__global__ void __launch_bounds__(256) gather_hop_bf(
    const int* __restrict__ rpU, const unsigned* __restrict__ ivU,
    const uint2* __restrict__ srcForU, uint2* __restrict__ outU,
    const int* __restrict__ rpI, const unsigned* __restrict__ ivI,
    const uint2* __restrict__ srcForI, uint2* __restrict__ outI) {
    const int lane = threadIdx.x & 63;
    const int sub = lane >> 4;
    const int r = lane & 15;
    const int wave = blockIdx.x * (blockDim.x >> 6) + (threadIdx.x >> 6);
    float4 acc; uint2* out; int row;
    if (wave < USER_NUM) {
        row = wave;
        acc = row_accum<true>(rpU, ivU, srcForU, row, sub, r);
        out = outU;
    } else if (wave < USER_NUM + ITEM_NUM) {
        row = wave - USER_NUM;
        acc = row_accum<false>(rpI, ivI, srcForI, row, sub, r);
        out = outI;
    } else return;
    if (sub == 0)
        out[row * 16 + r] = make_uint2(pack_bf2(acc.x, acc.y), pack_bf2(acc.z, acc.w));
}

// hop 3 fused: gcn = emb + 0.5*g1 + (1/3)*g2 + 0.25*acc, fp32 out
__global__ void __launch_bounds__(256) gather_hop3(
    const int* __restrict__ rpU, const unsigned* __restrict__ ivU,
    const uint2* __restrict__ srcForU,
    const int* __restrict__ rpI, const unsigned* __restrict__ ivI,
    const uint2* __restrict__ srcForI,
    const float4* __restrict__ embU, const uint2* __restrict__ g1u,
    const uint2* __restrict__ g2u, float4* __restrict__ gcnU,
    const float4* __restrict__ embI, const uint2* __restrict__ g1i,
    const uint2* __restrict__ g2i, float4* __restrict__ gcnI) {
    const int lane = threadIdx.x & 63;
    const int sub = lane >> 4;
    const int r = lane & 15;
    const int wave = blockIdx.x * (blockDim.x >> 6) + (threadIdx.x >> 6);
    float4 acc;
    const float4* emb; const uint2* g1; const uint2* g2; float4* gcn; int row;
    if (wave < USER_NUM) {
        row = wave;
        acc = row_accum<true>(rpU, ivU, srcForU, row, sub, r);
        emb = embU; g1 = g1u; g2 = g2u; gcn = gcnU;
    } else if (wave < USER_NUM + ITEM_NUM) {
        row = wave - USER_NUM;
        acc = row_accum<false>(rpI, ivI, srcForI, row, sub, r);
        emb = embI; g1 = g1i; g2 = g2i; gcn = gcnI;
    } else return;
    if (sub == 0) {
        const int o = row * 16 + r;
        const float4 e = emb[o];
        const uint2 p1 = g1[o];
        const uint2 p2 = g2[o];
        const float c3 = 1.0f / 3.0f;
        float4 g;
        g.x = e.x + 0.5f * bf_lo(p1.x) + c3 * bf_lo(p2.x) + 0.25f * acc.x;
        g.y = e.y + 0.5f * bf_hi(p1.x) + c3 * bf_hi(p2.x) + 0.25f * acc.y;
        g.z = e.z + 0.5f * bf_lo(p1.y) + c3 * bf_lo(p2.y) + 0.25f * acc.z;
        g.w = e.w + 0.5f * bf_hi(p1.y) + c3 * bf_hi(p2.y) + 0.25f * acc.w;
        gcn[o] = g;
    }
}

// ---------- losses ----------

__global__ void __launch_bounds__(256) bpr_loss(
    const int* __restrict__ user, const int* __restrict__ itemI,
    const int* __restrict__ itemJ,
    const float* __restrict__ gcnU, const float* __restrict__ gcnI,
    float* __restrict__ accs) {
    const int lane = threadIdx.x & 63;
    const int wave = blockIdx.x * (blockDim.x >> 6) + (threadIdx.x >> 6);
    if (wave >= NB) return;
    const int uu = user[wave], vi = itemI[wave], vj = itemJ[wave];
    const float u  = gcnU[uu * DD + lane];
    const float xi = gcnI[vi * DD + lane];
    const float xj = gcnI[vj * DD + lane];
    const float pi = waveReduceSum(u * xi);
    const float pj = waveReduceSum(u * xj);
    const float rg = waveReduceSum(u * u + xi * xi + xj * xj);
    if (lane == 0) {
        const float x = pi - pj;
        const float bpr = fmaxf(-x, 0.0f) + log1pf(expf(-fabsf(x)));
        const int slot = wave & (NSLOT - 1);
        unsafeAtomicAdd(&accs[0 * NSLOT + slot], bpr);
        unsafeAtomicAdd(&accs[1 * NSLOT + slot], rg);
    }
}

__global__ void __launch_bounds__(256) self_loss(
    const float* __restrict__ oldU, const float* __restrict__ oldI,
    const float* __restrict__ gcnU, const float* __restrict__ gcnI,
    const float* __restrict__ nU, const float* __restrict__ nI,
    float* __restrict__ accs) {
    const int lane = threadIdx.x & 63;
    const int wave = blockIdx.x * (blockDim.x >> 6) + (threadIdx.x >> 6);
    if (wave < USER_NUM) {
        const float d = oldU[wave * DD + lane] - gcnU[wave * DD + lane];
        const float s = waveReduceSum(d * d);
        if (lane == 0)
            unsafeAtomicAdd(&accs[2 * NSLOT + (wave & (NSLOT - 1))], sqrtf(s) * nU[wave]);
    } else if (wave < USER_NUM + ITEM_NUM) {
        const int r = wave - USER_NUM;
        const float d = oldI[r * DD + lane] - gcnI[r * DD + lane];
        const float s = waveReduceSum(d * d);
        if (lane == 0)
            unsafeAtomicAdd(&accs[3 * NSLOT + (r & (NSLOT - 1))], sqrtf(s) * nI[r]);
    }
}

__global__ void __launch_bounds__(64) finalize(const float* __restrict__ accs,
                                               float* __restrict__ out) {
    const int lane = threadIdx.x;
    float s[4];
#pragma unroll
    for (int k = 0; k < 4; k++) {
        float v = 0.0f;
        for (int j = lane; j < NSLOT; j += 64) v += accs[k * NSLOT + j];
        s[k] = waveReduceSum(v);
    }
    if (lane == 0) {
        const float loss_bpr = s[0] / NB + 1e-4f * (s[1] / NB);
        const float loss_self = s[2] / USER_NUM + s[3] / ITEM_NUM;
        out[0] = loss_bpr;
        out[1] = 100.0f * loss_self;
        out[2] = 1.0f;
        out[3] = 1.0f;
    }
}

extern "C" void kernel_launch(void* const* d_in, const int* in_sizes, int n_in,
                              void* d_out, int out_size, void* d_ws, size_t ws_size,
                              hipStream_t stream) {
    const int*   user     = (const int*)d_in[0];
    const int*   item_i   = (const int*)d_in[1];
    const int*   item_j   = (const int*)d_in[2];
    const int*   edge_u   = (const int*)d_in[3];
    const int*   edge_i   = (const int*)d_in[4];
    const float* edge_val = (const float*)d_in[5];
    const float* user_emb = (const float*)d_in[6];
    const float* item_emb = (const float*)d_in[7];
    const float* old_U    = (const float*)d_in[8];
    const float* old_I    = (const float*)d_in[9];
    const float* n_U      = (const float*)d_in[10];
    const float* n_I      = (const float*)d_in[11];
    float* out = (float*)d_out;

    char* base = (char*)d_ws;
    size_t off = 0;
    auto carve = [&](size_t bytes) {
        char* p = base + off;
        off += (bytes + 255) & ~(size_t)255;
        return p;
    };
    int*      coarseCnt = (int*)carve(NBK * 4);
    float*    accs      = (float*)carve(4 * NSLOT * 4);
    size_t zero_bytes = off;  // everything above must start zeroed
    int*      cbase = (int*)carve(NBK * 4);
    int*      ccur  = (int*)carve(NBK * 4);
    int*      rpU   = (int*)carve((USER_NUM + 1) * 4);
    int*      rpI   = (int*)carve((ITEM_NUM + 1) * 4);
    unsigned* ivU   = (unsigned*)carve((size_t)NEDGE * 4);
    unsigned* ivI   = (unsigned*)carve((size_t)NEDGE * 4);
    uint2*    ebU   = (uint2*)carve((size_t)USER_NUM * DD * 2);
    uint2*    ebI   = (uint2*)carve((size_t)ITEM_NUM * DD * 2);
    uint2*    g1u   = (uint2*)carve((size_t)USER_NUM * DD * 2);
    uint2*    g1i   = (uint2*)carve((size_t)ITEM_NUM * DD * 2);
    uint2*    g2u   = (uint2*)carve((size_t)USER_NUM * DD * 2);
    uint2*    g2i   = (uint2*)carve((size_t)ITEM_NUM * DD * 2);
    int2*     stU   = (int2*)carve((size_t)NEDGE * 8);   // staging, dead after binB
    int2*     stI   = (int2*)carve((size_t)NEDGE * 8);
    // gcn buffers alias staging (written only in hop3, after binB)
    float* gcnU = (float*)stU;   // 25.6 MB fits in stU's 25.6 MB
    float* gcnI = (float*)stI;   // 12.8 MB fits in stI's 25.6 MB

    hipMemsetAsync(d_ws, 0, zero_bytes, stream);

    const dim3 blk(256);

    cvt_kernel<<<(USER_NUM * 16 + 255) / 256, blk, 0, stream>>>(
        (const float4*)user_emb, ebU, USER_NUM * 16);
    cvt_kernel<<<(ITEM_NUM * 16 + 255) / 256, blk, 0, stream>>>(
        (const float4*)item_emb, ebI, ITEM_NUM * 16);

    coarse_hist<<<NTILE, blk, 0, stream>>>(edge_u, edge_i, coarseCnt);
    coarse_scan<<<1, 512, 0, stream>>>(coarseCnt, cbase, ccur);
    binA<<<NTILE, blk, 0, stream>>>(edge_u, edge_i, edge_val, ccur, stU, stI);
    binB<<<NBK, blk, 0, stream>>>(stU, stI, cbase, coarseCnt, rpU, rpI, ivU, ivI);

    const int rows = USER_NUM + ITEM_NUM;
    const int hop_grid = (rows + 3) / 4;

    gather_hop_bf<<<hop_grid, blk, 0, stream>>>(rpU, ivU, ebI, g1u,
                                                rpI, ivI, ebU, g1i);
    gather_hop_bf<<<hop_grid, blk, 0, stream>>>(rpU, ivU, g1i, g2u,
                                                rpI, ivI, g1u, g2i);
    gather_hop3<<<hop_grid, blk, 0, stream>>>(
        rpU, ivU, g2i, rpI, ivI, g2u,
        (const float4*)user_emb, g1u, g2u, (float4*)gcnU,
        (const float4*)item_emb, g1i, g2i, (float4*)gcnI);

    bpr_loss<<<(NB + 3) / 4, blk, 0, stream>>>(user, item_i, item_j, gcnU, gcnI, accs);
    self_loss<<<(rows + 3) / 4, blk, 0, stream>>>(
        old_U, old_I, gcnU, gcnI, n_U, n_I, accs);
    finalize<<<1, 64, 0, stream>>>(accs, out);
}

// Round 6
// 753.900 us; speedup vs baseline: 5.5872x; 1.2213x over previous
//
#include <hip/hip_runtime.h>

#define USER_NUM 100000
#define ITEM_NUM 50000
#define DD 64
#define NEDGE 3200000
#define NB 16384
#define NSLOT 256

#define TILE 8192
#define NTILE ((NEDGE + TILE - 1) / TILE)        // 391
#define USH 9                                    // user coarse bucket = 512 dests
#define ISH 8                                    // item coarse bucket = 256 dests
#define UBK ((USER_NUM + (1 << USH) - 1) >> USH) // 196
#define IBK ((ITEM_NUM + (1 << ISH) - 1) >> ISH) // 196
#define NBK (UBK + IBK)                          // 392

__device__ __forceinline__ float waveReduceSum(float x) {
#pragma unroll
    for (int off = 32; off > 0; off >>= 1)
        x += __shfl_down(x, off, 64);
    return x;
}

// ---- bf16 helpers ----
__device__ __forceinline__ unsigned pack_bf2(float a, float b) {
    unsigned ua = __float_as_uint(a), ub = __float_as_uint(b);
    ua = (ua + 0x7fffu + ((ua >> 16) & 1u)) >> 16;
    ub = (ub + 0x7fffu + ((ub >> 16) & 1u)) & 0xffff0000u;
    return ua | ub;
}
__device__ __forceinline__ float bf_lo(unsigned u) { return __uint_as_float(u << 16); }
__device__ __forceinline__ float bf_hi(unsigned u) { return __uint_as_float(u & 0xffff0000u); }
__device__ __forceinline__ unsigned roundbf(unsigned y) {  // fp32 bits -> bf16 bits (RNE)
    return (y + 0x7fffu + ((y >> 16) & 1u)) >> 16;
}

// fp32 table -> bf16 table (uint2 = 4 features)
__global__ void __launch_bounds__(256) cvt_kernel(
    const float4* __restrict__ src, uint2* __restrict__ dst, int n4) {
    int t = blockIdx.x * blockDim.x + threadIdx.x;
    if (t < n4) {
        float4 f = src[t];
        dst[t] = make_uint2(pack_bf2(f.x, f.y), pack_bf2(f.z, f.w));
    }
}

// ---------- two-level binned counting sort ----------
__global__ void __launch_bounds__(256) coarse_hist(
    const int* __restrict__ eu, const int* __restrict__ ei,
    int* __restrict__ coarseCnt) {
    __shared__ int lc[NBK];
    const int t = threadIdx.x;
    for (int j = t; j < NBK; j += 256) lc[j] = 0;
    __syncthreads();
    const int tb = blockIdx.x * TILE;
    for (int k = 0; k < TILE / 256; k++) {
        int e = tb + k * 256 + t;
        if (e < NEDGE) {
            atomicAdd(&lc[eu[e] >> USH], 1);
            atomicAdd(&lc[UBK + (ei[e] >> ISH)], 1);
        }
    }
    __syncthreads();
    for (int j = t; j < NBK; j += 256)
        if (lc[j]) atomicAdd(&coarseCnt[j], lc[j]);
}

__global__ void __launch_bounds__(512) coarse_scan(
    const int* __restrict__ cnt, int* __restrict__ base, int* __restrict__ cur) {
    __shared__ int a[512];
    const int t = threadIdx.x;
    int v = (t < UBK) ? cnt[t] : 0;
    a[t] = v;
    __syncthreads();
    for (int off = 1; off < 512; off <<= 1) {
        int x = (t >= off) ? a[t - off] : 0;
        __syncthreads();
        a[t] += x;
        __syncthreads();
    }
    if (t < UBK) { base[t] = a[t] - v; cur[t] = a[t] - v; }
    __syncthreads();
    v = (t < IBK) ? cnt[UBK + t] : 0;
    a[t] = v;
    __syncthreads();
    for (int off = 1; off < 512; off <<= 1) {
        int x = (t >= off) ? a[t - off] : 0;
        __syncthreads();
        a[t] += x;
        __syncthreads();
    }
    if (t < IBK) { base[UBK + t] = a[t] - v; cur[UBK + t] = a[t] - v; }
}

__global__ void __launch_bounds__(256) binA(
    const int* __restrict__ eu, const int* __restrict__ ei,
    const float* __restrict__ ev,
    int* __restrict__ coarseCur, int2* __restrict__ stU, int2* __restrict__ stI) {
    __shared__ int lc[NBK];
    const int t = threadIdx.x;
    for (int j = t; j < NBK; j += 256) lc[j] = 0;
    __syncthreads();
    const int tb = blockIdx.x * TILE;
    for (int k = 0; k < TILE / 256; k++) {
        int e = tb + k * 256 + t;
        if (e < NEDGE) {
            atomicAdd(&lc[eu[e] >> USH], 1);
            atomicAdd(&lc[UBK + (ei[e] >> ISH)], 1);
        }
    }
    __syncthreads();
    for (int j = t; j < NBK; j += 256) {
        int c = lc[j];
        lc[j] = c ? atomicAdd(&coarseCur[j], c) : 0;
    }
    __syncthreads();
    for (int k = 0; k < TILE / 256; k++) {
        int e = tb + k * 256 + t;
        if (e < NEDGE) {
            int u = eu[e], i = ei[e], vb = __float_as_int(ev[e]);
            int pu = atomicAdd(&lc[u >> USH], 1);
            stU[pu] = make_int2(((u & ((1 << USH) - 1)) << 16) | i, vb);
            int pi = atomicAdd(&lc[UBK + (i >> ISH)], 1);
            stI[pi] = make_int2(((i & ((1 << ISH) - 1)) << 17) | u, vb);
        }
    }
}

__global__ void __launch_bounds__(256) binB(
    const int2* __restrict__ stU, const int2* __restrict__ stI,
    const int* __restrict__ base, const int* __restrict__ cnt,
    int* __restrict__ rpU, int* __restrict__ rpI,
    unsigned* __restrict__ ivU, unsigned* __restrict__ ivI) {
    __shared__ int h[512];
    const int t = threadIdx.x;
    const int b = blockIdx.x;
    if (b < UBK) {
        const int s = base[b], n = cnt[b];
        const int dbase = b << USH;
        h[t] = 0; h[t + 256] = 0;
        __syncthreads();
        for (int p = s + t; p < s + n; p += 256)
            atomicAdd(&h[(unsigned)stU[p].x >> 16], 1);
        __syncthreads();
        int o0 = h[t], o1 = h[t + 256];
        for (int off = 1; off < 512; off <<= 1) {
            int x0 = (t >= off) ? h[t - off] : 0;
            int x1 = (t + 256 >= off) ? h[t + 256 - off] : 0;
            __syncthreads();
            h[t] += x0; h[t + 256] += x1;
            __syncthreads();
        }
        int e0 = s + h[t] - o0, e1 = s + h[t + 256] - o1;
        __syncthreads();
        h[t] = e0; h[t + 256] = e1;
        if (dbase + t < USER_NUM) rpU[dbase + t] = e0;
        if (dbase + 256 + t < USER_NUM) rpU[dbase + 256 + t] = e1;
        if (t == 0 && dbase + 512 >= USER_NUM) rpU[USER_NUM] = s + n;
        __syncthreads();
        for (int p = s + t; p < s + n; p += 256) {
            int2 en = stU[p];
            unsigned x = (unsigned)en.x;
            int pos = atomicAdd(&h[x >> 16], 1);
            unsigned bf = roundbf((unsigned)en.y);
            ivU[pos] = (bf << 16) | (x & 0xFFFFu);
        }
    } else {
        const int ib = b - UBK;
        const int s = base[b], n = cnt[b];
        const int dbase = ib << ISH;
        h[t] = 0;
        __syncthreads();
        for (int p = s + t; p < s + n; p += 256)
            atomicAdd(&h[(unsigned)stI[p].x >> 17], 1);
        __syncthreads();
        int o0 = h[t];
        for (int off = 1; off < 256; off <<= 1) {
            int x0 = (t >= off) ? h[t - off] : 0;
            __syncthreads();
            h[t] += x0;
            __syncthreads();
        }
        int e0 = s + h[t] - o0;
        __syncthreads();
        h[t] = e0;
        if (dbase + t < ITEM_NUM) rpI[dbase + t] = e0;
        if (t == 0 && dbase + 256 >= ITEM_NUM) rpI[ITEM_NUM] = s + n;
        __syncthreads();
        for (int p = s + t; p < s + n; p += 256) {
            int2 en = stI[p];
            unsigned x = (unsigned)en.x;
            int pos = atomicAdd(&h[x >> 17], 1);
            unsigned v15 = roundbf((unsigned)en.y) & 0x7FFFu;
            ivI[pos] = (v15 << 17) | (x & 0x1FFFFu);
        }
    }
}

// ---------- gather hop core ----------
template<bool ISU>
__device__ __forceinline__ float4 row_accum(
    const int* __restrict__ rp, const unsigned* __restrict__ iv,
    const uint2* __restrict__ src, int row, int sub, int r) {
    const int s = rp[row], e2 = rp[row + 1];
    float4 a0 = make_float4(0.f, 0.f, 0.f, 0.f);
    float4 a1 = make_float4(0.f, 0.f, 0.f, 0.f);
    int t = s + sub;
    for (; t + 4 < e2; t += 8) {
        const unsigned q0 = iv[t];
        const unsigned q1 = iv[t + 4];
        const float v0 = ISU ? __uint_as_float(q0 & 0xFFFF0000u)
                             : __uint_as_float((q0 >> 17) << 16);
        const float v1 = ISU ? __uint_as_float(q1 & 0xFFFF0000u)
                             : __uint_as_float((q1 >> 17) << 16);
        const int x0 = ISU ? (int)(q0 & 0xFFFFu) : (int)(q0 & 0x1FFFFu);
        const int x1 = ISU ? (int)(q1 & 0xFFFFu) : (int)(q1 & 0x1FFFFu);
        const uint2 b0 = src[x0 * 16 + r];
        const uint2 b1 = src[x1 * 16 + r];
        a0.x += v0 * bf_lo(b0.x); a0.y += v0 * bf_hi(b0.x);
        a0.z += v0 * bf_lo(b0.y); a0.w += v0 * bf_hi(b0.y);
        a1.x += v1 * bf_lo(b1.x); a1.y += v1 * bf_hi(b1.x);
        a1.z += v1 * bf_lo(b1.y); a1.w += v1 * bf_hi(b1.y);
    }
    if (t < e2) {
        const unsigned q0 = iv[t];
        const float v0 = ISU ? __uint_as_float(q0 & 0xFFFF0000u)
                             : __uint_as_float((q0 >> 17) << 16);
        const int x0 = ISU ? (int)(q0 & 0xFFFFu) : (int)(q0 & 0x1FFFFu);
        const uint2 b0 = src[x0 * 16 + r];
        a0.x += v0 * bf_lo(b0.x); a0.y += v0 * bf_hi(b0.x);
        a0.z += v0 * bf_lo(b0.y); a0.w += v0 * bf_hi(b0.y);
    }
    float4 acc;
    acc.x = a0.x + a1.x; acc.y = a0.y + a1.y;
    acc.z = a0.z + a1.z; acc.w = a0.w + a1.w;
#pragma unroll
    for (int off = 16; off <= 32; off <<= 1) {
        acc.x += __shfl_xor(acc.x, off, 64);
        acc.y += __shfl_xor(acc.y, off, 64);
        acc.z += __shfl_xor(acc.z, off, 64);
        acc.w += __shfl_xor(acc.w, off, 64);
    }
    return acc;  // valid on sub==0
}

__global__ void __launch_bounds__(256) gather_hop_bf(
    const int* __restrict__ rpU, const unsigned* __restrict__ ivU,
    const uint2* __restrict__ srcForU, uint2* __restrict__ outU,
    const int* __restrict__ rpI, const unsigned* __restrict__ ivI,
    const uint2* __restrict__ srcForI, uint2* __restrict__ outI) {
    const int lane = threadIdx.x & 63;
    const int sub = lane >> 4;
    const int r = lane & 15;
    const int wave = blockIdx.x * (blockDim.x >> 6) + (threadIdx.x >> 6);
    float4 acc; uint2* out; int row;
    if (wave < USER_NUM) {
        row = wave;
        acc = row_accum<true>(rpU, ivU, srcForU, row, sub, r);
        out = outU;
    } else if (wave < USER_NUM + ITEM_NUM) {
        row = wave - USER_NUM;
        acc = row_accum<false>(rpI, ivI, srcForI, row, sub, r);
        out = outI;
    } else return;
    if (sub == 0)
        out[row * 16 + r] = make_uint2(pack_bf2(acc.x, acc.y), pack_bf2(acc.z, acc.w));
}

__global__ void __launch_bounds__(256) gather_hop3(
    const int* __restrict__ rpU, const unsigned* __restrict__ ivU,
    const uint2* __restrict__ srcForU,
    const int* __restrict__ rpI, const unsigned* __restrict__ ivI,
    const uint2* __restrict__ srcForI,
    const float4* __restrict__ embU, const uint2* __restrict__ g1u,
    const uint2* __restrict__ g2u, float4* __restrict__ gcnU,
    const float4* __restrict__ embI, const uint2* __restrict__ g1i,
    const uint2* __restrict__ g2i, float4* __restrict__ gcnI) {
    const int lane = threadIdx.x & 63;
    const int sub = lane >> 4;
    const int r = lane & 15;
    const int wave = blockIdx.x * (blockDim.x >> 6) + (threadIdx.x >> 6);
    float4 acc;
    const float4* emb; const uint2* g1; const uint2* g2; float4* gcn; int row;
    if (wave < USER_NUM) {
        row = wave;
        acc = row_accum<true>(rpU, ivU, srcForU, row, sub, r);
        emb = embU; g1 = g1u; g2 = g2u; gcn = gcnU;
    } else if (wave < USER_NUM + ITEM_NUM) {
        row = wave - USER_NUM;
        acc = row_accum<false>(rpI, ivI, srcForI, row, sub, r);
        emb = embI; g1 = g1i; g2 = g2i; gcn = gcnI;
    } else return;
    if (sub == 0) {
        const int o = row * 16 + r;
        const float4 e = emb[o];
        const uint2 p1 = g1[o];
        const uint2 p2 = g2[o];
        const float c3 = 1.0f / 3.0f;
        float4 g;
        g.x = e.x + 0.5f * bf_lo(p1.x) + c3 * bf_lo(p2.x) + 0.25f * acc.x;
        g.y = e.y + 0.5f * bf_hi(p1.x) + c3 * bf_hi(p2.x) + 0.25f * acc.y;
        g.z = e.z + 0.5f * bf_lo(p1.y) + c3 * bf_lo(p2.y) + 0.25f * acc.z;
        g.w = e.w + 0.5f * bf_hi(p1.y) + c3 * bf_hi(p2.y) + 0.25f * acc.w;
        gcn[o] = g;
    }
}

// ---------- losses: grid-stride, register accumulation, 1 atomic/wave ----------
// 16 lanes per row (lane r loads float4 r), 4 rows per wave-iteration.

__global__ void __launch_bounds__(256) bpr_loss(
    const int* __restrict__ user, const int* __restrict__ itemI,
    const int* __restrict__ itemJ,
    const float4* __restrict__ gcnU4, const float4* __restrict__ gcnI4,
    float* __restrict__ accs) {
    const int lane = threadIdx.x & 63;
    const int sub = lane >> 4;
    const int r = lane & 15;
    const int W = blockIdx.x * 4 + (threadIdx.x >> 6);
    const int NW = gridDim.x * 4;
    float accB = 0.0f, accR = 0.0f;
    for (int g = W; g < NB / 4; g += NW) {
        const int samp = g * 4 + sub;
        const int uu = user[samp], vi = itemI[samp], vj = itemJ[samp];
        const float4 u  = gcnU4[uu * 16 + r];
        const float4 xi = gcnI4[vi * 16 + r];
        const float4 xj = gcnI4[vj * 16 + r];
        float pi = u.x * xi.x + u.y * xi.y + u.z * xi.z + u.w * xi.w;
        float pj = u.x * xj.x + u.y * xj.y + u.z * xj.z + u.w * xj.w;
        float rg = u.x * u.x + u.y * u.y + u.z * u.z + u.w * u.w
                 + xi.x * xi.x + xi.y * xi.y + xi.z * xi.z + xi.w * xi.w
                 + xj.x * xj.x + xj.y * xj.y + xj.z * xj.z + xj.w * xj.w;
#pragma unroll
        for (int off = 1; off <= 8; off <<= 1) {
            pi += __shfl_xor(pi, off, 64);
            pj += __shfl_xor(pj, off, 64);
            rg += __shfl_xor(rg, off, 64);
        }
        if (r == 0) {
            const float x = pi - pj;
            accB += fmaxf(-x, 0.0f) + log1pf(expf(-fabsf(x)));
            accR += rg;
        }
    }
    accB = waveReduceSum(accB);
    accR = waveReduceSum(accR);
    if (lane == 0) {
        const int slot = W & (NSLOT - 1);
        unsafeAtomicAdd(&accs[0 * NSLOT + slot], accB);
        unsafeAtomicAdd(&accs[1 * NSLOT + slot], accR);
    }
}

__global__ void __launch_bounds__(256) self_loss(
    const float4* __restrict__ oldU4, const float4* __restrict__ oldI4,
    const float4* __restrict__ gcnU4, const float4* __restrict__ gcnI4,
    const float* __restrict__ nU, const float* __restrict__ nI,
    float* __restrict__ accs) {
    const int lane = threadIdx.x & 63;
    const int sub = lane >> 4;
    const int r = lane & 15;
    const int W = blockIdx.x * 4 + (threadIdx.x >> 6);
    const int NW = gridDim.x * 4;
    const int ngroups = (USER_NUM + ITEM_NUM) / 4;  // 37500, exact
    float accU = 0.0f, accI = 0.0f;
    for (int g = W; g < ngroups; g += NW) {
        const int row = g * 4 + sub;
        const bool isU = row < USER_NUM;
        const int rr = isU ? row : row - USER_NUM;
        const float4 o  = isU ? oldU4[rr * 16 + r] : oldI4[rr * 16 + r];
        const float4 gg = isU ? gcnU4[rr * 16 + r] : gcnI4[rr * 16 + r];
        const float dx = o.x - gg.x, dy = o.y - gg.y;
        const float dz = o.z - gg.z, dw = o.w - gg.w;
        float s = dx * dx + dy * dy + dz * dz + dw * dw;
#pragma unroll
        for (int off = 1; off <= 8; off <<= 1)
            s += __shfl_xor(s, off, 64);
        if (r == 0) {
            const float val = sqrtf(s) * (isU ? nU[rr] : nI[rr]);
            if (isU) accU += val; else accI += val;
        }
    }
    accU = waveReduceSum(accU);
    accI = waveReduceSum(accI);
    if (lane == 0) {
        const int slot = W & (NSLOT - 1);
        unsafeAtomicAdd(&accs[2 * NSLOT + slot], accU);
        unsafeAtomicAdd(&accs[3 * NSLOT + slot], accI);
    }
}

__global__ void __launch_bounds__(64) finalize(const float* __restrict__ accs,
                                               float* __restrict__ out) {
    const int lane = threadIdx.x;
    float s[4];
#pragma unroll
    for (int k = 0; k < 4; k++) {
        float v = 0.0f;
        for (int j = lane; j < NSLOT; j += 64) v += accs[k * NSLOT + j];
        s[k] = waveReduceSum(v);
    }
    if (lane == 0) {
        const float loss_bpr = s[0] / NB + 1e-4f * (s[1] / NB);
        const float loss_self = s[2] / USER_NUM + s[3] / ITEM_NUM;
        out[0] = loss_bpr;
        out[1] = 100.0f * loss_self;
        out[2] = 1.0f;
        out[3] = 1.0f;
    }
}

extern "C" void kernel_launch(void* const* d_in, const int* in_sizes, int n_in,
                              void* d_out, int out_size, void* d_ws, size_t ws_size,
                              hipStream_t stream) {
    const int*   user     = (const int*)d_in[0];
    const int*   item_i   = (const int*)d_in[1];
    const int*   item_j   = (const int*)d_in[2];
    const int*   edge_u   = (const int*)d_in[3];
    const int*   edge_i   = (const int*)d_in[4];
    const float* edge_val = (const float*)d_in[5];
    const float* user_emb = (const float*)d_in[6];
    const float* item_emb = (const float*)d_in[7];
    const float* old_U    = (const float*)d_in[8];
    const float* old_I    = (const float*)d_in[9];
    const float* n_U      = (const float*)d_in[10];
    const float* n_I      = (const float*)d_in[11];
    float* out = (float*)d_out;

    char* base = (char*)d_ws;
    size_t off = 0;
    auto carve = [&](size_t bytes) {
        char* p = base + off;
        off += (bytes + 255) & ~(size_t)255;
        return p;
    };
    int*      coarseCnt = (int*)carve(NBK * 4);
    float*    accs      = (float*)carve(4 * NSLOT * 4);
    size_t zero_bytes = off;  // everything above must start zeroed
    int*      cbase = (int*)carve(NBK * 4);
    int*      ccur  = (int*)carve(NBK * 4);
    int*      rpU   = (int*)carve((USER_NUM + 1) * 4);
    int*      rpI   = (int*)carve((ITEM_NUM + 1) * 4);
    unsigned* ivU   = (unsigned*)carve((size_t)NEDGE * 4);
    unsigned* ivI   = (unsigned*)carve((size_t)NEDGE * 4);
    uint2*    ebU   = (uint2*)carve((size_t)USER_NUM * DD * 2);
    uint2*    ebI   = (uint2*)carve((size_t)ITEM_NUM * DD * 2);
    uint2*    g1u   = (uint2*)carve((size_t)USER_NUM * DD * 2);
    uint2*    g1i   = (uint2*)carve((size_t)ITEM_NUM * DD * 2);
    uint2*    g2u   = (uint2*)carve((size_t)USER_NUM * DD * 2);
    uint2*    g2i   = (uint2*)carve((size_t)ITEM_NUM * DD * 2);
    int2*     stU   = (int2*)carve((size_t)NEDGE * 8);   // staging, dead after binB
    int2*     stI   = (int2*)carve((size_t)NEDGE * 8);
    float* gcnU = (float*)stU;   // aliases staging (hop3 runs after binB)
    float* gcnI = (float*)stI;

    hipMemsetAsync(d_ws, 0, zero_bytes, stream);

    const dim3 blk(256);

    cvt_kernel<<<(USER_NUM * 16 + 255) / 256, blk, 0, stream>>>(
        (const float4*)user_emb, ebU, USER_NUM * 16);
    cvt_kernel<<<(ITEM_NUM * 16 + 255) / 256, blk, 0, stream>>>(
        (const float4*)item_emb, ebI, ITEM_NUM * 16);

    coarse_hist<<<NTILE, blk, 0, stream>>>(edge_u, edge_i, coarseCnt);
    coarse_scan<<<1, 512, 0, stream>>>(coarseCnt, cbase, ccur);
    binA<<<NTILE, blk, 0, stream>>>(edge_u, edge_i, edge_val, ccur, stU, stI);
    binB<<<NBK, blk, 0, stream>>>(stU, stI, cbase, coarseCnt, rpU, rpI, ivU, ivI);

    const int rows = USER_NUM + ITEM_NUM;
    const int hop_grid = (rows + 3) / 4;

    gather_hop_bf<<<hop_grid, blk, 0, stream>>>(rpU, ivU, ebI, g1u,
                                                rpI, ivI, ebU, g1i);
    gather_hop_bf<<<hop_grid, blk, 0, stream>>>(rpU, ivU, g1i, g2u,
                                                rpI, ivI, g1u, g2i);
    gather_hop3<<<hop_grid, blk, 0, stream>>>(
        rpU, ivU, g2i, rpI, ivI, g2u,
        (const float4*)user_emb, g1u, g2u, (float4*)gcnU,
        (const float4*)item_emb, g1i, g2i, (float4*)gcnI);

    bpr_loss<<<128, blk, 0, stream>>>(user, item_i, item_j,
                                      (const float4*)gcnU, (const float4*)gcnI, accs);
    self_loss<<<256, blk, 0, stream>>>(
        (const float4*)old_U, (const float4*)old_I,
        (const float4*)gcnU, (const float4*)gcnI, n_U, n_I, accs);
    finalize<<<1, 64, 0, stream>>>(accs, out);
}

// Round 7
// 646.332 us; speedup vs baseline: 6.5170x; 1.1664x over previous
//
#include <hip/hip_runtime.h>

#define USER_NUM 100000
#define ITEM_NUM 50000
#define DD 64
#define NEDGE 3200000
#define NB 16384
#define NSLOT 256

#define TILE 8192
#define NTILE ((NEDGE + TILE - 1) / TILE)        // 391
#define USH 9                                    // user coarse bucket = 512 dests
#define ISH 8                                    // item coarse bucket = 256 dests
#define UBK ((USER_NUM + (1 << USH) - 1) >> USH) // 196
#define IBK ((ITEM_NUM + (1 << ISH) - 1) >> ISH) // 196
#define NBK (UBK + IBK)                          // 392

#define FP8_SCALE 64.0f   // all fp8 tables hold value*64 (avoids e4m3 subnormals)

typedef float v2f __attribute__((ext_vector_type(2)));

__device__ __forceinline__ float waveReduceSum(float x) {
#pragma unroll
    for (int off = 32; off > 0; off >>= 1)
        x += __shfl_down(x, off, 64);
    return x;
}

__device__ __forceinline__ unsigned roundbf(unsigned y) {  // fp32 bits -> bf16 bits (RNE)
    return (y + 0x7fffu + ((y >> 16) & 1u)) >> 16;
}

// ---- fp8 e4m3 helpers (HW cvt; 8 fp8 in a uint2) ----
__device__ __forceinline__ void dec8(const uint2 b, float* f) {
    v2f f0 = __builtin_amdgcn_cvt_pk_f32_fp8(b.x, false);
    v2f f1 = __builtin_amdgcn_cvt_pk_f32_fp8(b.x, true);
    v2f f2 = __builtin_amdgcn_cvt_pk_f32_fp8(b.y, false);
    v2f f3 = __builtin_amdgcn_cvt_pk_f32_fp8(b.y, true);
    f[0] = f0.x; f[1] = f0.y; f[2] = f1.x; f[3] = f1.y;
    f[4] = f2.x; f[5] = f2.y; f[6] = f3.x; f[7] = f3.y;
}
__device__ __forceinline__ void fma8(const uint2 b, const float v, float* a) {
    v2f f0 = __builtin_amdgcn_cvt_pk_f32_fp8(b.x, false);
    v2f f1 = __builtin_amdgcn_cvt_pk_f32_fp8(b.x, true);
    v2f f2 = __builtin_amdgcn_cvt_pk_f32_fp8(b.y, false);
    v2f f3 = __builtin_amdgcn_cvt_pk_f32_fp8(b.y, true);
    a[0] += v * f0.x; a[1] += v * f0.y; a[2] += v * f1.x; a[3] += v * f1.y;
    a[4] += v * f2.x; a[5] += v * f2.y; a[6] += v * f3.x; a[7] += v * f3.y;
}
__device__ __forceinline__ uint2 pack_fp8x8(const float* a) {
    int lo = 0, hi = 0;
    lo = __builtin_amdgcn_cvt_pk_fp8_f32(a[0], a[1], lo, false);
    lo = __builtin_amdgcn_cvt_pk_fp8_f32(a[2], a[3], lo, true);
    hi = __builtin_amdgcn_cvt_pk_fp8_f32(a[4], a[5], hi, false);
    hi = __builtin_amdgcn_cvt_pk_fp8_f32(a[6], a[7], hi, true);
    return make_uint2((unsigned)lo, (unsigned)hi);
}

// fp32 table -> fp8 table, scaled by FP8_SCALE. One thread = 8 features.
__global__ void __launch_bounds__(256) cvt8_kernel(
    const float4* __restrict__ src, uint2* __restrict__ dst, int n8) {
    int t = blockIdx.x * blockDim.x + threadIdx.x;
    if (t < n8) {
        float4 a = src[2 * t], b = src[2 * t + 1];
        float f[8] = {a.x * FP8_SCALE, a.y * FP8_SCALE, a.z * FP8_SCALE, a.w * FP8_SCALE,
                      b.x * FP8_SCALE, b.y * FP8_SCALE, b.z * FP8_SCALE, b.w * FP8_SCALE};
        dst[t] = pack_fp8x8(f);
    }
}

// ---------- two-level binned counting sort (unchanged from R5) ----------
__global__ void __launch_bounds__(256) coarse_hist(
    const int* __restrict__ eu, const int* __restrict__ ei,
    int* __restrict__ coarseCnt) {
    __shared__ int lc[NBK];
    const int t = threadIdx.x;
    for (int j = t; j < NBK; j += 256) lc[j] = 0;
    __syncthreads();
    const int tb = blockIdx.x * TILE;
    for (int k = 0; k < TILE / 256; k++) {
        int e = tb + k * 256 + t;
        if (e < NEDGE) {
            atomicAdd(&lc[eu[e] >> USH], 1);
            atomicAdd(&lc[UBK + (ei[e] >> ISH)], 1);
        }
    }
    __syncthreads();
    for (int j = t; j < NBK; j += 256)
        if (lc[j]) atomicAdd(&coarseCnt[j], lc[j]);
}

__global__ void __launch_bounds__(512) coarse_scan(
    const int* __restrict__ cnt, int* __restrict__ base, int* __restrict__ cur) {
    __shared__ int a[512];
    const int t = threadIdx.x;
    int v = (t < UBK) ? cnt[t] : 0;
    a[t] = v;
    __syncthreads();
    for (int off = 1; off < 512; off <<= 1) {
        int x = (t >= off) ? a[t - off] : 0;
        __syncthreads();
        a[t] += x;
        __syncthreads();
    }
    if (t < UBK) { base[t] = a[t] - v; cur[t] = a[t] - v; }
    __syncthreads();
    v = (t < IBK) ? cnt[UBK + t] : 0;
    a[t] = v;
    __syncthreads();
    for (int off = 1; off < 512; off <<= 1) {
        int x = (t >= off) ? a[t - off] : 0;
        __syncthreads();
        a[t] += x;
        __syncthreads();
    }
    if (t < IBK) { base[UBK + t] = a[t] - v; cur[UBK + t] = a[t] - v; }
}

__global__ void __launch_bounds__(256) binA(
    const int* __restrict__ eu, const int* __restrict__ ei,
    const float* __restrict__ ev,
    int* __restrict__ coarseCur, int2* __restrict__ stU, int2* __restrict__ stI) {
    __shared__ int lc[NBK];
    const int t = threadIdx.x;
    for (int j = t; j < NBK; j += 256) lc[j] = 0;
    __syncthreads();
    const int tb = blockIdx.x * TILE;
    for (int k = 0; k < TILE / 256; k++) {
        int e = tb + k * 256 + t;
        if (e < NEDGE) {
            atomicAdd(&lc[eu[e] >> USH], 1);
            atomicAdd(&lc[UBK + (ei[e] >> ISH)], 1);
        }
    }
    __syncthreads();
    for (int j = t; j < NBK; j += 256) {
        int c = lc[j];
        lc[j] = c ? atomicAdd(&coarseCur[j], c) : 0;
    }
    __syncthreads();
    for (int k = 0; k < TILE / 256; k++) {
        int e = tb + k * 256 + t;
        if (e < NEDGE) {
            int u = eu[e], i = ei[e], vb = __float_as_int(ev[e]);
            int pu = atomicAdd(&lc[u >> USH], 1);
            stU[pu] = make_int2(((u & ((1 << USH) - 1)) << 16) | i, vb);
            int pi = atomicAdd(&lc[UBK + (i >> ISH)], 1);
            stI[pi] = make_int2(((i & ((1 << ISH) - 1)) << 17) | u, vb);
        }
    }
}

__global__ void __launch_bounds__(256) binB(
    const int2* __restrict__ stU, const int2* __restrict__ stI,
    const int* __restrict__ base, const int* __restrict__ cnt,
    int* __restrict__ rpU, int* __restrict__ rpI,
    unsigned* __restrict__ ivU, unsigned* __restrict__ ivI) {
    __shared__ int h[512];
    const int t = threadIdx.x;
    const int b = blockIdx.x;
    if (b < UBK) {
        const int s = base[b], n = cnt[b];
        const int dbase = b << USH;
        h[t] = 0; h[t + 256] = 0;
        __syncthreads();
        for (int p = s + t; p < s + n; p += 256)
            atomicAdd(&h[(unsigned)stU[p].x >> 16], 1);
        __syncthreads();
        int o0 = h[t], o1 = h[t + 256];
        for (int off = 1; off < 512; off <<= 1) {
            int x0 = (t >= off) ? h[t - off] : 0;
            int x1 = (t + 256 >= off) ? h[t + 256 - off] : 0;
            __syncthreads();
            h[t] += x0; h[t + 256] += x1;
            __syncthreads();
        }
        int e0 = s + h[t] - o0, e1 = s + h[t + 256] - o1;
        __syncthreads();
        h[t] = e0; h[t + 256] = e1;
        if (dbase + t < USER_NUM) rpU[dbase + t] = e0;
        if (dbase + 256 + t < USER_NUM) rpU[dbase + 256 + t] = e1;
        if (t == 0 && dbase + 512 >= USER_NUM) rpU[USER_NUM] = s + n;
        __syncthreads();
        for (int p = s + t; p < s + n; p += 256) {
            int2 en = stU[p];
            unsigned x = (unsigned)en.x;
            int pos = atomicAdd(&h[x >> 16], 1);
            unsigned bf = roundbf((unsigned)en.y);
            ivU[pos] = (bf << 16) | (x & 0xFFFFu);
        }
    } else {
        const int ib = b - UBK;
        const int s = base[b], n = cnt[b];
        const int dbase = ib << ISH;
        h[t] = 0;
        __syncthreads();
        for (int p = s + t; p < s + n; p += 256)
            atomicAdd(&h[(unsigned)stI[p].x >> 17], 1);
        __syncthreads();
        int o0 = h[t];
        for (int off = 1; off < 256; off <<= 1) {
            int x0 = (t >= off) ? h[t - off] : 0;
            __syncthreads();
            h[t] += x0;
            __syncthreads();
        }
        int e0 = s + h[t] - o0;
        __syncthreads();
        h[t] = e0;
        if (dbase + t < ITEM_NUM) rpI[dbase + t] = e0;
        if (t == 0 && dbase + 256 >= ITEM_NUM) rpI[ITEM_NUM] = s + n;
        __syncthreads();
        for (int p = s + t; p < s + n; p += 256) {
            int2 en = stI[p];
            unsigned x = (unsigned)en.x;
            int pos = atomicAdd(&h[x >> 17], 1);
            unsigned v15 = roundbf((unsigned)en.y) & 0x7FFFu;
            ivI[pos] = (v15 << 17) | (x & 0x1FFFFu);
        }
    }
}

// ---------- gather hop core: fp8 source rows (64 B = 1 line), fp32 accumulate ----
// lane = sub*8 + r: sub in [0,8) picks edge stream, r in [0,8) picks uint2 chunk.
template<bool ISU>
__device__ __forceinline__ void row_accum8(
    const int* __restrict__ rp, const unsigned* __restrict__ iv,
    const uint2* __restrict__ src, int row, int sub, int r, float* acc) {
    const int s = rp[row], e2 = rp[row + 1];
    float a0[8] = {0, 0, 0, 0, 0, 0, 0, 0};
    float a1[8] = {0, 0, 0, 0, 0, 0, 0, 0};
    int t = s + sub;
    for (; t + 8 < e2; t += 16) {
        const unsigned q0 = iv[t];
        const unsigned q1 = iv[t + 8];
        const float v0 = ISU ? __uint_as_float(q0 & 0xFFFF0000u)
                             : __uint_as_float((q0 >> 17) << 16);
        const float v1 = ISU ? __uint_as_float(q1 & 0xFFFF0000u)
                             : __uint_as_float((q1 >> 17) << 16);
        const int x0 = ISU ? (int)(q0 & 0xFFFFu) : (int)(q0 & 0x1FFFFu);
        const int x1 = ISU ? (int)(q1 & 0xFFFFu) : (int)(q1 & 0x1FFFFu);
        const uint2 b0 = src[x0 * 8 + r];
        const uint2 b1 = src[x1 * 8 + r];
        fma8(b0, v0, a0);
        fma8(b1, v1, a1);
    }
    if (t < e2) {
        const unsigned q0 = iv[t];
        const float v0 = ISU ? __uint_as_float(q0 & 0xFFFF0000u)
                             : __uint_as_float((q0 >> 17) << 16);
        const int x0 = ISU ? (int)(q0 & 0xFFFFu) : (int)(q0 & 0x1FFFFu);
        const uint2 b0 = src[x0 * 8 + r];
        fma8(b0, v0, a0);
    }
#pragma unroll
    for (int k = 0; k < 8; k++) acc[k] = a0[k] + a1[k];
#pragma unroll
    for (int off = 8; off <= 32; off <<= 1) {
#pragma unroll
        for (int k = 0; k < 8; k++) acc[k] += __shfl_xor(acc[k], off, 64);
    }
    // valid on sub==0
}

// hops 1 & 2: fp8 out (acc is value*FP8_SCALE already — pack directly)
__global__ void __launch_bounds__(256) gather_hop_f8(
    const int* __restrict__ rpU, const unsigned* __restrict__ ivU,
    const uint2* __restrict__ srcForU, uint2* __restrict__ outU,
    const int* __restrict__ rpI, const unsigned* __restrict__ ivI,
    const uint2* __restrict__ srcForI, uint2* __restrict__ outI) {
    const int lane = threadIdx.x & 63;
    const int sub = lane >> 3;
    const int r = lane & 7;
    const int wave = blockIdx.x * 4 + (threadIdx.x >> 6);
    float acc[8];
    uint2* out; int row;
    if (wave < USER_NUM) {
        row = wave;
        row_accum8<true>(rpU, ivU, srcForU, row, sub, r, acc);
        out = outU;
    } else if (wave < USER_NUM + ITEM_NUM) {
        row = wave - USER_NUM;
        row_accum8<false>(rpI, ivI, srcForI, row, sub, r, acc);
        out = outI;
    } else return;
    if (sub == 0) out[row * 8 + r] = pack_fp8x8(acc);
}

// hop 3 fused: gcn = emb + (0.5*g1s + (1/3)*g2s + 0.25*accs)/FP8_SCALE, fp32 out
__global__ void __launch_bounds__(256) gather_hop3(
    const int* __restrict__ rpU, const unsigned* __restrict__ ivU,
    const uint2* __restrict__ srcForU,
    const int* __restrict__ rpI, const unsigned* __restrict__ ivI,
    const uint2* __restrict__ srcForI,
    const float4* __restrict__ embU, const uint2* __restrict__ g1u,
    const uint2* __restrict__ g2u, float4* __restrict__ gcnU,
    const float4* __restrict__ embI, const uint2* __restrict__ g1i,
    const uint2* __restrict__ g2i, float4* __restrict__ gcnI) {
    const int lane = threadIdx.x & 63;
    const int sub = lane >> 3;
    const int r = lane & 7;
    const int wave = blockIdx.x * 4 + (threadIdx.x >> 6);
    float acc[8];
    const float4* emb; const uint2* g1; const uint2* g2; float4* gcn; int row;
    if (wave < USER_NUM) {
        row = wave;
        row_accum8<true>(rpU, ivU, srcForU, row, sub, r, acc);
        emb = embU; g1 = g1u; g2 = g2u; gcn = gcnU;
    } else if (wave < USER_NUM + ITEM_NUM) {
        row = wave - USER_NUM;
        row_accum8<false>(rpI, ivI, srcForI, row, sub, r, acc);
        emb = embI; g1 = g1i; g2 = g2i; gcn = gcnI;
    } else return;
    if (sub == 0) {
        const float C1 = 0.5f / FP8_SCALE;
        const float C2 = (1.0f / 3.0f) / FP8_SCALE;
        const float C3 = 0.25f / FP8_SCALE;
        float f1[8], f2[8];
        dec8(g1[row * 8 + r], f1);
        dec8(g2[row * 8 + r], f2);
        const float4 e0 = emb[row * 16 + 2 * r];
        const float4 e1 = emb[row * 16 + 2 * r + 1];
        float4 o0, o1;
        o0.x = e0.x + C1 * f1[0] + C2 * f2[0] + C3 * acc[0];
        o0.y = e0.y + C1 * f1[1] + C2 * f2[1] + C3 * acc[1];
        o0.z = e0.z + C1 * f1[2] + C2 * f2[2] + C3 * acc[2];
        o0.w = e0.w + C1 * f1[3] + C2 * f2[3] + C3 * acc[3];
        o1.x = e1.x + C1 * f1[4] + C2 * f2[4] + C3 * acc[4];
        o1.y = e1.y + C1 * f1[5] + C2 * f2[5] + C3 * acc[5];
        o1.z = e1.z + C1 * f1[6] + C2 * f2[6] + C3 * acc[6];
        o1.w = e1.w + C1 * f1[7] + C2 * f2[7] + C3 * acc[7];
        gcn[row * 16 + 2 * r] = o0;
        gcn[row * 16 + 2 * r + 1] = o1;
    }
}

// ---------- losses (unchanged from R6) ----------
__global__ void __launch_bounds__(256) bpr_loss(
    const int* __restrict__ user, const int* __restrict__ itemI,
    const int* __restrict__ itemJ,
    const float4* __restrict__ gcnU4, const float4* __restrict__ gcnI4,
    float* __restrict__ accs) {
    const int lane = threadIdx.x & 63;
    const int sub = lane >> 4;
    const int r = lane & 15;
    const int W = blockIdx.x * 4 + (threadIdx.x >> 6);
    const int NW = gridDim.x * 4;
    float accB = 0.0f, accR = 0.0f;
    for (int g = W; g < NB / 4; g += NW) {
        const int samp = g * 4 + sub;
        const int uu = user[samp], vi = itemI[samp], vj = itemJ[samp];
        const float4 u  = gcnU4[uu * 16 + r];
        const float4 xi = gcnI4[vi * 16 + r];
        const float4 xj = gcnI4[vj * 16 + r];
        float pi = u.x * xi.x + u.y * xi.y + u.z * xi.z + u.w * xi.w;
        float pj = u.x * xj.x + u.y * xj.y + u.z * xj.z + u.w * xj.w;
        float rg = u.x * u.x + u.y * u.y + u.z * u.z + u.w * u.w
                 + xi.x * xi.x + xi.y * xi.y + xi.z * xi.z + xi.w * xi.w
                 + xj.x * xj.x + xj.y * xj.y + xj.z * xj.z + xj.w * xj.w;
#pragma unroll
        for (int off = 1; off <= 8; off <<= 1) {
            pi += __shfl_xor(pi, off, 64);
            pj += __shfl_xor(pj, off, 64);
            rg += __shfl_xor(rg, off, 64);
        }
        if (r == 0) {
            const float x = pi - pj;
            accB += fmaxf(-x, 0.0f) + log1pf(expf(-fabsf(x)));
            accR += rg;
        }
    }
    accB = waveReduceSum(accB);
    accR = waveReduceSum(accR);
    if (lane == 0) {
        const int slot = W & (NSLOT - 1);
        unsafeAtomicAdd(&accs[0 * NSLOT + slot], accB);
        unsafeAtomicAdd(&accs[1 * NSLOT + slot], accR);
    }
}

__global__ void __launch_bounds__(256) self_loss(
    const float4* __restrict__ oldU4, const float4* __restrict__ oldI4,
    const float4* __restrict__ gcnU4, const float4* __restrict__ gcnI4,
    const float* __restrict__ nU, const float* __restrict__ nI,
    float* __restrict__ accs) {
    const int lane = threadIdx.x & 63;
    const int sub = lane >> 4;
    const int r = lane & 15;
    const int W = blockIdx.x * 4 + (threadIdx.x >> 6);
    const int NW = gridDim.x * 4;
    const int ngroups = (USER_NUM + ITEM_NUM) / 4;
    float accU = 0.0f, accI = 0.0f;
    for (int g = W; g < ngroups; g += NW) {
        const int row = g * 4 + sub;
        const bool isU = row < USER_NUM;
        const int rr = isU ? row : row - USER_NUM;
        const float4 o  = isU ? oldU4[rr * 16 + r] : oldI4[rr * 16 + r];
        const float4 gg = isU ? gcnU4[rr * 16 + r] : gcnI4[rr * 16 + r];
        const float dx = o.x - gg.x, dy = o.y - gg.y;
        const float dz = o.z - gg.z, dw = o.w - gg.w;
        float s = dx * dx + dy * dy + dz * dz + dw * dw;
#pragma unroll
        for (int off = 1; off <= 8; off <<= 1)
            s += __shfl_xor(s, off, 64);
        if (r == 0) {
            const float val = sqrtf(s) * (isU ? nU[rr] : nI[rr]);
            if (isU) accU += val; else accI += val;
        }
    }
    accU = waveReduceSum(accU);
    accI = waveReduceSum(accI);
    if (lane == 0) {
        const int slot = W & (NSLOT - 1);
        unsafeAtomicAdd(&accs[2 * NSLOT + slot], accU);
        unsafeAtomicAdd(&accs[3 * NSLOT + slot], accI);
    }
}

__global__ void __launch_bounds__(64) finalize(const float* __restrict__ accs,
                                               float* __restrict__ out) {
    const int lane = threadIdx.x;
    float s[4];
#pragma unroll
    for (int k = 0; k < 4; k++) {
        float v = 0.0f;
        for (int j = lane; j < NSLOT; j += 64) v += accs[k * NSLOT + j];
        s[k] = waveReduceSum(v);
    }
    if (lane == 0) {
        const float loss_bpr = s[0] / NB + 1e-4f * (s[1] / NB);
        const float loss_self = s[2] / USER_NUM + s[3] / ITEM_NUM;
        out[0] = loss_bpr;
        out[1] = 100.0f * loss_self;
        out[2] = 1.0f;
        out[3] = 1.0f;
    }
}

extern "C" void kernel_launch(void* const* d_in, const int* in_sizes, int n_in,
                              void* d_out, int out_size, void* d_ws, size_t ws_size,
                              hipStream_t stream) {
    const int*   user     = (const int*)d_in[0];
    const int*   item_i   = (const int*)d_in[1];
    const int*   item_j   = (const int*)d_in[2];
    const int*   edge_u   = (const int*)d_in[3];
    const int*   edge_i   = (const int*)d_in[4];
    const float* edge_val = (const float*)d_in[5];
    const float* user_emb = (const float*)d_in[6];
    const float* item_emb = (const float*)d_in[7];
    const float* old_U    = (const float*)d_in[8];
    const float* old_I    = (const float*)d_in[9];
    const float* n_U      = (const float*)d_in[10];
    const float* n_I      = (const float*)d_in[11];
    float* out = (float*)d_out;

    char* base = (char*)d_ws;
    size_t off = 0;
    auto carve = [&](size_t bytes) {
        char* p = base + off;
        off += (bytes + 255) & ~(size_t)255;
        return p;
    };
    int*      coarseCnt = (int*)carve(NBK * 4);
    float*    accs      = (float*)carve(4 * NSLOT * 4);
    size_t zero_bytes = off;  // everything above must start zeroed
    int*      cbase = (int*)carve(NBK * 4);
    int*      ccur  = (int*)carve(NBK * 4);
    int*      rpU   = (int*)carve((USER_NUM + 1) * 4);
    int*      rpI   = (int*)carve((ITEM_NUM + 1) * 4);
    unsigned* ivU   = (unsigned*)carve((size_t)NEDGE * 4);
    unsigned* ivI   = (unsigned*)carve((size_t)NEDGE * 4);
    uint2*    ebU8  = (uint2*)carve((size_t)USER_NUM * DD);  // fp8 tables (1 B/elem)
    uint2*    ebI8  = (uint2*)carve((size_t)ITEM_NUM * DD);
    uint2*    g1u8  = (uint2*)carve((size_t)USER_NUM * DD);
    uint2*    g1i8  = (uint2*)carve((size_t)ITEM_NUM * DD);
    uint2*    g2u8  = (uint2*)carve((size_t)USER_NUM * DD);
    uint2*    g2i8  = (uint2*)carve((size_t)ITEM_NUM * DD);
    int2*     stU   = (int2*)carve((size_t)NEDGE * 8);   // staging, dead after binB
    int2*     stI   = (int2*)carve((size_t)NEDGE * 8);
    float* gcnU = (float*)stU;   // aliases staging (hop3 runs after binB)
    float* gcnI = (float*)stI;

    hipMemsetAsync(d_ws, 0, zero_bytes, stream);

    const dim3 blk(256);

    cvt8_kernel<<<(USER_NUM * 8 + 255) / 256, blk, 0, stream>>>(
        (const float4*)user_emb, ebU8, USER_NUM * 8);
    cvt8_kernel<<<(ITEM_NUM * 8 + 255) / 256, blk, 0, stream>>>(
        (const float4*)item_emb, ebI8, ITEM_NUM * 8);

    coarse_hist<<<NTILE, blk, 0, stream>>>(edge_u, edge_i, coarseCnt);
    coarse_scan<<<1, 512, 0, stream>>>(coarseCnt, cbase, ccur);
    binA<<<NTILE, blk, 0, stream>>>(edge_u, edge_i, edge_val, ccur, stU, stI);
    binB<<<NBK, blk, 0, stream>>>(stU, stI, cbase, coarseCnt, rpU, rpI, ivU, ivI);

    const int rows = USER_NUM + ITEM_NUM;
    const int hop_grid = (rows + 3) / 4;

    gather_hop_f8<<<hop_grid, blk, 0, stream>>>(rpU, ivU, ebI8, g1u8,
                                                rpI, ivI, ebU8, g1i8);
    gather_hop_f8<<<hop_grid, blk, 0, stream>>>(rpU, ivU, g1i8, g2u8,
                                                rpI, ivI, g1u8, g2i8);
    gather_hop3<<<hop_grid, blk, 0, stream>>>(
        rpU, ivU, g2i8, rpI, ivI, g2u8,
        (const float4*)user_emb, g1u8, g2u8, (float4*)gcnU,
        (const float4*)item_emb, g1i8, g2i8, (float4*)gcnI);

    bpr_loss<<<128, blk, 0, stream>>>(user, item_i, item_j,
                                      (const float4*)gcnU, (const float4*)gcnI, accs);
    self_loss<<<256, blk, 0, stream>>>(
        (const float4*)old_U, (const float4*)old_I,
        (const float4*)gcnU, (const float4*)gcnI, n_U, n_I, accs);
    finalize<<<1, 64, 0, stream>>>(accs, out);
}